// Round 24
// baseline (343.874 us; speedup 1.0000x reference)
//
#include <hip/hip_runtime.h>
#include <hip/hip_fp16.h>
#include <math.h>

#define BB 4
#define CC 32
#define KK 4
#define SS 4
#define NN 65536

constexpr int NCOMP = 64;
constexpr int SSTRIDE = 1088;
constexpr int PSTRIDE = 1128;
constexpr int NB = 128;
constexpr float EPS_ = 1e-6f;
constexpr float COVREG_ = 1e-4f;
constexpr float LOG2PI_C = 1.8378770664093453f;

__device__ constexpr int XOFF_[32] = {
    0,   4,   8,   12,  16,  24,  32,  40,  48,  60,  72,
    84,  96,  112, 128, 144, 160, 180, 200, 220, 240, 264,
    288, 312, 336, 364, 392, 420, 448, 480, 512, 544};

typedef _Float16 half8 __attribute__((ext_vector_type(8)));
typedef _Float16 half4 __attribute__((ext_vector_type(4)));
typedef float floatx4 __attribute__((ext_vector_type(4)));

// ---------------------------------------------------------------------------
// Kernel 1: iter-0 stats via MFMA (unchanged).
// ---------------------------------------------------------------------------
template <bool ITER0, int CHUNKS>
__global__ __launch_bounds__(256, 2) void gmm_accum_mfma(
    const float* __restrict__ feat, const int* __restrict__ labels,
    const float* __restrict__ resp, float* __restrict__ partials) {
  __shared__ __align__(16) _Float16 fC[32 * 48];
  __shared__ __align__(16) _Float16 respH[4][32];
  __shared__ __align__(16) _Float16 maskH[4][32];

  const int t = threadIdx.x;
  const int b = blockIdx.y;
  const int blk0 = blockIdx.x * (CHUNKS * 32);
  const int k = t >> 6;
  const int l = t & 63;
  const int row16 = l & 15;
  const int kg = l >> 4;

  floatx4 acc[4][7];
#pragma unroll
  for (int s = 0; s < 4; ++s)
#pragma unroll
    for (int j = 0; j < 7; ++j) acc[s][j] = (floatx4){0.f, 0.f, 0.f, 0.f};

  const int cstage = t >> 3;
  const int n4 = (t & 7) * 4;

  float4 pf;
  float4 presp = make_float4(0, 0, 0, 0);
  int plab = 0;
  pf = *(const float4*)(feat + ((size_t)b * CC + cstage) * NN + blk0 + n4);
  if (t < 32) {
    plab = labels[b * NN + blk0 + t];
    if (!ITER0) presp = *(const float4*)(resp + ((size_t)b * NN + blk0 + t) * 4);
  }

  const half8 hz = {0, 0, 0, 0, 0, 0, 0, 0};

  for (int chunk = 0; chunk < CHUNKS; ++chunk) {
    {
      half4 hv;
      hv[0] = (_Float16)pf.x;
      hv[1] = (_Float16)pf.y;
      hv[2] = (_Float16)pf.z;
      hv[3] = (_Float16)pf.w;
      *(half4*)&fC[cstage * 48 + n4] = hv;
    }
    if (t < 32) {
      if (ITER0) {
        const int cmp = (blk0 + chunk * 32 + t) & 3;
        respH[0][t] = (cmp == 0) ? (_Float16)1 : (_Float16)0;
        respH[1][t] = (cmp == 1) ? (_Float16)1 : (_Float16)0;
        respH[2][t] = (cmp == 2) ? (_Float16)1 : (_Float16)0;
        respH[3][t] = (cmp == 3) ? (_Float16)1 : (_Float16)0;
      } else {
        respH[0][t] = (_Float16)presp.x;
        respH[1][t] = (_Float16)presp.y;
        respH[2][t] = (_Float16)presp.z;
        respH[3][t] = (_Float16)presp.w;
      }
      maskH[0][t] = (plab == 0) ? (_Float16)1 : (_Float16)0;
      maskH[1][t] = (plab == 1) ? (_Float16)1 : (_Float16)0;
      maskH[2][t] = (plab == 2) ? (_Float16)1 : (_Float16)0;
      maskH[3][t] = (plab == 3) ? (_Float16)1 : (_Float16)0;
    }
    __syncthreads();

    if (chunk < CHUNKS - 1) {
      const int n0n = blk0 + (chunk + 1) * 32;
      pf = *(const float4*)(feat + ((size_t)b * CC + cstage) * NN + n0n + n4);
      if (t < 32) {
        plab = labels[b * NN + n0n + t];
        if (!ITER0)
          presp = *(const float4*)(resp + ((size_t)b * NN + n0n + t) * 4);
      }
    }

    const half8 ff0 = *(const half8*)&fC[row16 * 48 + kg * 8];
    const half8 ff1 = *(const half8*)&fC[(row16 + 16) * 48 + kg * 8];

    const half8 mh = *(const half8*)&maskH[k][kg * 8];
    const half8 H0 = ff0 * mh;
    const half8 H1 = ff1 * mh;
    const half8 agB = (row16 == 0) ? mh : hz;

#pragma unroll
    for (int s = 0; s < 4; ++s) {
      const half8 rh = *(const half8*)&respH[s][kg * 8];
      const half8 G0 = ff0 * rh;
      const half8 G1 = ff1 * rh;
      const half8 agA = (row16 == 0) ? rh : hz;
      acc[s][0] =
          __builtin_amdgcn_mfma_f32_16x16x32_f16(G0, H0, acc[s][0], 0, 0, 0);
      acc[s][1] =
          __builtin_amdgcn_mfma_f32_16x16x32_f16(G0, H1, acc[s][1], 0, 0, 0);
      acc[s][2] =
          __builtin_amdgcn_mfma_f32_16x16x32_f16(G1, H0, acc[s][2], 0, 0, 0);
      acc[s][3] =
          __builtin_amdgcn_mfma_f32_16x16x32_f16(G1, H1, acc[s][3], 0, 0, 0);
      acc[s][4] =
          __builtin_amdgcn_mfma_f32_16x16x32_f16(G0, agB, acc[s][4], 0, 0, 0);
      acc[s][5] =
          __builtin_amdgcn_mfma_f32_16x16x32_f16(G1, agB, acc[s][5], 0, 0, 0);
      acc[s][6] =
          __builtin_amdgcn_mfma_f32_16x16x32_f16(agA, agB, acc[s][6], 0, 0, 0);
    }
    __syncthreads();
  }

#pragma unroll
  for (int s = 0; s < 4; ++s) {
    float* sg = partials + ((size_t)(b * gridDim.x + blockIdx.x) * 16 +
                            (k * 4 + s)) *
                               SSTRIDE;
    const int dr = kg * 4;
#pragma unroll
    for (int r = 0; r < 4; ++r) {
      sg[(dr + r) * 32 + row16] = acc[s][0][r];
      sg[(dr + r) * 32 + 16 + row16] = acc[s][1][r];
      sg[(16 + dr + r) * 32 + row16] = acc[s][2][r];
      sg[(16 + dr + r) * 32 + 16 + row16] = acc[s][3][r];
    }
    if (row16 == 0) {
#pragma unroll
      for (int r = 0; r < 4; ++r) {
        sg[1024 + dr + r] = acc[s][4][r];
        sg[1024 + 16 + dr + r] = acc[s][5][r];
      }
    }
    if (l == 0) sg[1056] = acc[s][6][0];
  }
}

// ---------------------------------------------------------------------------
// Kernel F: fused E+M (unchanged from R23).
// ---------------------------------------------------------------------------
template <int TILES>
__global__ __launch_bounds__(256, 2) void gmm_fused(
    const float* __restrict__ feat, const int* __restrict__ labels,
    const float* __restrict__ params, float* __restrict__ partials) {
  __shared__ __align__(16) _Float16 fTd[2 * 64 * 56];
  __shared__ __align__(16) _Float16 fCd[2 * 32 * 72];
  __shared__ int4 xlds4[2048];
  __shared__ float zlds[16 * 32];  // -z
  __shared__ float c0lds[16];
  __shared__ int lab_lds[2][64];
  __shared__ __align__(16) _Float16 respHd[2][4][64];
  __shared__ __align__(16) _Float16 maskHd[2][4][64];

  const int t = threadIdx.x;
  const int b = blockIdx.y;
  const int blk0 = blockIdx.x * (TILES * 64);
  const int w = t >> 6;
  const int l = t & 63;
  const int row16 = l & 15;
  const int kg = l >> 4;

  for (int idx = t; idx < 2048; idx += 256) {
    const int c = idx >> 7, chunk = idx & 127;
    xlds4[idx] = *(const int4*)((const char*)(params +
                                              (size_t)(b * 16 + c) * PSTRIDE +
                                              612) +
                                chunk * 16);
  }
  for (int idx = t; idx < 16 * 32; idx += 256) {
    zlds[idx] =
        -params[(size_t)(b * 16 + (idx >> 5)) * PSTRIDE + 576 + (idx & 31)];
  }
  if (t < 16) c0lds[t] = params[(size_t)(b * 16 + t) * PSTRIDE + 608];

  const _Float16* xl = (const _Float16*)xlds4;
  const int cload = t >> 4;
  const int i4 = (t & 15) * 4;
  const half8 hz = {0, 0, 0, 0, 0, 0, 0, 0};

  floatx4 acc[4][7];
#pragma unroll
  for (int s = 0; s < 4; ++s)
#pragma unroll
    for (int j = 0; j < 7; ++j) acc[s][j] = (floatx4){0.f, 0.f, 0.f, 0.f};

  float4 pv0 = *(const float4*)(feat + ((size_t)b * CC + cload) * NN + blk0 + i4);
  float4 pv1 =
      *(const float4*)(feat + ((size_t)b * CC + cload + 16) * NN + blk0 + i4);
  int plab = (t < 64) ? labels[b * NN + blk0 + t] : 0;

  for (int tile = 0; tile < TILES; ++tile) {
    const int base = blk0 + tile * 64;
    const int bs = tile & 1;
    _Float16* fT = &fTd[bs * (64 * 56)];
    _Float16* fC = &fCd[bs * (32 * 72)];

    {
      const _Float16 h0x = (_Float16)pv0.x, h0y = (_Float16)pv0.y;
      const _Float16 h0z = (_Float16)pv0.z, h0w = (_Float16)pv0.w;
      const _Float16 h1x = (_Float16)pv1.x, h1y = (_Float16)pv1.y;
      const _Float16 h1z = (_Float16)pv1.z, h1w = (_Float16)pv1.w;
      fT[(i4 + 0) * 56 + cload] = h0x;
      fT[(i4 + 1) * 56 + cload] = h0y;
      fT[(i4 + 2) * 56 + cload] = h0z;
      fT[(i4 + 3) * 56 + cload] = h0w;
      fT[(i4 + 0) * 56 + cload + 16] = h1x;
      fT[(i4 + 1) * 56 + cload + 16] = h1y;
      fT[(i4 + 2) * 56 + cload + 16] = h1z;
      fT[(i4 + 3) * 56 + cload + 16] = h1w;
      half4 a, c2;
      a[0] = h0x; a[1] = h0y; a[2] = h0z; a[3] = h0w;
      c2[0] = h1x; c2[1] = h1y; c2[2] = h1z; c2[3] = h1w;
      *(half4*)&fC[cload * 72 + i4] = a;
      *(half4*)&fC[(cload + 16) * 72 + i4] = c2;
      if (t < 64) lab_lds[bs][t] = plab;
    }
    __syncthreads();  // sync1

    if (tile < TILES - 1) {
      const int nb2 = base + 64;
      pv0 = *(const float4*)(feat + ((size_t)b * CC + cload) * NN + nb2 + i4);
      pv1 = *(const float4*)(feat + ((size_t)b * CC + cload + 16) * NN + nb2 +
                             i4);
      if (t < 64) plab = labels[b * NN + nb2 + t];
    }

    // ---- E-core ----
    const half8 bfr = *(const half8*)&fT[(w * 16 + row16) * 56 + kg * 8];
    const int lab = lab_lds[bs][w * 16 + row16];

    float lp0 = 0.f, lp1 = 0.f, lp2 = 0.f, lp3 = 0.f;
#pragma unroll
    for (int c = 0; c < 16; ++c) {
      const half8 a0 = *(const half8*)&xl[c * 1024 + (0 * 64 + l) * 8];
      const half8 a1 = *(const half8*)&xl[c * 1024 + (1 * 64 + l) * 8];
      const floatx4 cin0 = *(const floatx4*)&zlds[c * 32 + kg * 4];
      const floatx4 cin1 = *(const floatx4*)&zlds[c * 32 + 16 + kg * 4];
      floatx4 y0 =
          __builtin_amdgcn_mfma_f32_16x16x32_f16(a0, bfr, cin0, 0, 0, 0);
      floatx4 y1 =
          __builtin_amdgcn_mfma_f32_16x16x32_f16(a1, bfr, cin1, 0, 0, 0);
      float q = 0.f;
      q = fmaf(y0[0], y0[0], q);
      q = fmaf(y0[1], y0[1], q);
      q = fmaf(y0[2], y0[2], q);
      q = fmaf(y0[3], y0[3], q);
      q = fmaf(y1[0], y1[0], q);
      q = fmaf(y1[1], y1[1], q);
      q = fmaf(y1[2], y1[2], q);
      q = fmaf(y1[3], y1[3], q);
      q += __shfl_xor(q, 16);
      q += __shfl_xor(q, 32);
      const float lp = c0lds[c] - 0.5f * q;
      const bool own = (c >> 2) == lab;
      const int s = c & 3;
      lp0 = (own && s == 0) ? lp : lp0;
      lp1 = (own && s == 1) ? lp : lp1;
      lp2 = (own && s == 2) ? lp : lp2;
      lp3 = (own && s == 3) ? lp : lp3;
    }

    {
      const float m = fmaxf(fmaxf(lp0, lp1), fmaxf(lp2, lp3));
      const float e0 = expf(lp0 - m), e1 = expf(lp1 - m);
      const float e2 = expf(lp2 - m), e3 = expf(lp3 - m);
      const float inv = 1.f / (e0 + e1 + e2 + e3);
      if (l < 16) {
        const int e = w * 16 + l;
        respHd[bs][0][e] = (_Float16)(e0 * inv);
        respHd[bs][1][e] = (_Float16)(e1 * inv);
        respHd[bs][2][e] = (_Float16)(e2 * inv);
        respHd[bs][3][e] = (_Float16)(e3 * inv);
      }
      if (t < 64) {
        const int lb2 = lab_lds[bs][t];
        maskHd[bs][0][t] = (lb2 == 0) ? (_Float16)1 : (_Float16)0;
        maskHd[bs][1][t] = (lb2 == 1) ? (_Float16)1 : (_Float16)0;
        maskHd[bs][2][t] = (lb2 == 2) ? (_Float16)1 : (_Float16)0;
        maskHd[bs][3][t] = (lb2 == 3) ? (_Float16)1 : (_Float16)0;
      }
    }
    __syncthreads();  // sync2

    // ---- M-core ----
#pragma unroll
    for (int h = 0; h < 2; ++h) {
      const int eb = h * 32;
      const half8 ff0 = *(const half8*)&fC[row16 * 72 + eb + kg * 8];
      const half8 ff1 = *(const half8*)&fC[(row16 + 16) * 72 + eb + kg * 8];

      const half8 mh = *(const half8*)&maskHd[bs][w][eb + kg * 8];
      const half8 H0 = ff0 * mh;
      const half8 H1 = ff1 * mh;
      const half8 agB = (row16 == 0) ? mh : hz;

#pragma unroll
      for (int s = 0; s < 4; ++s) {
        const half8 rh = *(const half8*)&respHd[bs][s][eb + kg * 8];
        const half8 G0 = ff0 * rh;
        const half8 G1 = ff1 * rh;
        const half8 agA = (row16 == 0) ? rh : hz;
        acc[s][0] =
            __builtin_amdgcn_mfma_f32_16x16x32_f16(G0, H0, acc[s][0], 0, 0, 0);
        acc[s][1] =
            __builtin_amdgcn_mfma_f32_16x16x32_f16(G0, H1, acc[s][1], 0, 0, 0);
        acc[s][2] =
            __builtin_amdgcn_mfma_f32_16x16x32_f16(G1, H0, acc[s][2], 0, 0, 0);
        acc[s][3] =
            __builtin_amdgcn_mfma_f32_16x16x32_f16(G1, H1, acc[s][3], 0, 0, 0);
        acc[s][4] =
            __builtin_amdgcn_mfma_f32_16x16x32_f16(G0, agB, acc[s][4], 0, 0, 0);
        acc[s][5] =
            __builtin_amdgcn_mfma_f32_16x16x32_f16(G1, agB, acc[s][5], 0, 0, 0);
        acc[s][6] = __builtin_amdgcn_mfma_f32_16x16x32_f16(agA, agB, acc[s][6],
                                                           0, 0, 0);
      }
    }
  }

#pragma unroll
  for (int s = 0; s < 4; ++s) {
    float* sg = partials + ((size_t)(b * gridDim.x + blockIdx.x) * 16 +
                            (w * 4 + s)) *
                               SSTRIDE;
    const int dr = kg * 4;
#pragma unroll
    for (int r = 0; r < 4; ++r) {
      sg[(dr + r) * 32 + row16] = acc[s][0][r];
      sg[(dr + r) * 32 + 16 + row16] = acc[s][1][r];
      sg[(16 + dr + r) * 32 + row16] = acc[s][2][r];
      sg[(16 + dr + r) * 32 + 16 + row16] = acc[s][3][r];
    }
    if (row16 == 0) {
#pragma unroll
      for (int r = 0; r < 4; ++r) {
        sg[1024 + dr + r] = acc[s][4][r];
        sg[1024 + 16 + dr + r] = acc[s][5][r];
      }
    }
    if (l == 0) sg[1056] = acc[s][6][0];
  }
}

// ---------------------------------------------------------------------------
// NEW Kernel RP: merged reduce + params.  One block per comp, 256 threads.
// Phase 1: cooperative reduce of this comp's nb partials into LDS (coalesced,
// 2-accum ILP) + sibling-w reduce (128 threads).  Phase 2: the proven
// register/shfl Cholesky on wave 0 reading LDS; epilogue verbatim.
// Removes 3 launches + the stats global round-trip per EM iteration.
// ---------------------------------------------------------------------------
__global__ __launch_bounds__(256) void gmm_reduce_params(
    const float* __restrict__ part, float* __restrict__ params, int nb) {
  __shared__ float sl[1060];
  __shared__ float wpart[4][32];
  __shared__ float wsib[4];
  __shared__ float Xl[32 * 33];
  __shared__ float mul[32];

  const int t = threadIdx.x;
  const int comp = blockIdx.x;
  const int b = comp >> 4, cl = comp & 15;
  const size_t stride = (size_t)16 * SSTRIDE;
  const float* src0 = part + ((size_t)(b * nb) * 16 + cl) * SSTRIDE;

  // phase 1: reduce all 1057 cells
  for (int cell = t; cell < 1057; cell += 256) {
    const float* src = src0 + cell;
    float s0 = 0.f, s1 = 0.f;
#pragma unroll 8
    for (int blk = 0; blk < nb; blk += 2) {
      s0 += src[(size_t)blk * stride];
      s1 += src[(size_t)(blk + 1) * stride];
    }
    sl[cell] = s0 + s1;
  }
  // phase 1b: sibling w sums (for pi)
  if (t < 128) {
    const int sib = (cl & ~3) + (t >> 5);
    const int lane = t & 31;
    const float* srcw =
        part + ((size_t)(b * nb) * 16 + sib) * SSTRIDE + 1056;
    float s = 0.f;
    for (int q = lane; q < nb; q += 32) s += srcw[(size_t)q * stride];
    wpart[t >> 5][lane] = s;
  }
  __syncthreads();
  if (t < 4) {
    float s = 0.f;
#pragma unroll
    for (int j = 0; j < 32; ++j) s += wpart[t][j];
    wsib[t] = s;
  }

  // phase 2: wave-0 register/shfl Cholesky (verbatim, sg -> sl)
  float ldet = 0.f;
  if (t < 64) {
    const int i = t & 31;
    const float w = sl[1056];
    const float invw = 1.f / (w + EPS_);
    const float mu_i = sl[1024 + i] * invw;

    float a[32];
#pragma unroll
    for (int j4 = 0; j4 < 8; ++j4) {
      const float4 v = *(const float4*)(sl + i * 32 + 4 * j4);
      a[4 * j4 + 0] = v.x;
      a[4 * j4 + 1] = v.y;
      a[4 * j4 + 2] = v.z;
      a[4 * j4 + 3] = v.w;
    }
#pragma unroll
    for (int j = 0; j < 32; ++j) {
      const float muj = sl[1024 + j] * invw;
      float v = fmaf(a[j], invw, -mu_i * muj);
      v = (j == i) ? v + COVREG_ : v;
      a[j] = v;
    }

    float rd[32];
#pragma unroll
    for (int j = 0; j < 32; ++j) {
      const float diag = __shfl(a[j], j);
      ldet += logf(diag);
      const float rinv = rsqrtf(diag);
      rd[j] = rinv;
      const float lij = a[j] * rinv;
      a[j] = (i >= j) ? lij : a[j];
#pragma unroll
      for (int m = j + 1; m < 32; ++m) {
        const float Lmj = __shfl(lij, m);
        a[m] = (i >= m) ? fmaf(-lij, Lmj, a[m]) : a[m];
      }
    }

    float x[32];
#pragma unroll
    for (int m = 0; m < 32; ++m) {
      float s = (m == i) ? 1.f : 0.f;
#pragma unroll
      for (int r = 0; r < m; ++r) {
        const float Lmr = __shfl(a[r], m);
        s = fmaf(-Lmr, x[r], s);
      }
      x[m] = s * rd[m];
    }

    if (t < 32) {
#pragma unroll
      for (int m = 0; m < 32; ++m) Xl[m * 33 + i] = x[m];
      mul[i] = mu_i;
    }
  }
  __syncthreads();

  float* pg = params + (size_t)comp * PSTRIDE;
  for (int r = 0; r < 32; ++r) {
    const int L4 = 4 * ((r >> 2) + 1);
    if (t < L4) pg[XOFF_[r] + t] = (t <= r) ? Xl[r * 33 + t] : 0.f;
  }
  if (t < 64) {
    __half* xh = (__half*)(pg + 612);
#pragma unroll
    for (int th = 0; th < 2; ++th) {
      const int row = th * 16 + (t & 15);
      const int k0 = (t >> 4) * 8;
#pragma unroll
      for (int j = 0; j < 8; ++j) {
        const int k = k0 + j;
        const float v = (k <= row) ? Xl[row * 33 + k] : 0.f;
        xh[(th * 64 + t) * 8 + j] = __float2half(v);
      }
    }
  }
  if (t < 32) {
    float z = 0.f;
    for (int j = 0; j <= t; ++j) z += Xl[t * 33 + j] * mul[j];
    pg[576 + t] = z;
  }
  if (t == 0) {
    const float w = sl[1056];
    const float wsum = wsib[0] + wsib[1] + wsib[2] + wsib[3];
    const float pi = (w + EPS_) / (wsum + SS * EPS_);
    pg[608] = logf(pi) - 0.5f * (CC * LOG2PI_C + ldet);
  }
}

// ---------------------------------------------------------------------------
// Kernel 1b: reduce (fallback path only now).
// ---------------------------------------------------------------------------
__global__ __launch_bounds__(256) void gmm_reduce(const float* __restrict__ part,
                                                  float* __restrict__ stats,
                                                  int nb) {
  const int idx = blockIdx.x * 256 + threadIdx.x;
  if (idx >= NCOMP * 1057) return;
  const int comp = idx / 1057;
  const int cell = idx - comp * 1057;
  const int b = comp >> 4, cl = comp & 15;
  const float* src = part + ((size_t)(b * nb) * 16 + cl) * SSTRIDE + cell;
  const size_t stride = (size_t)16 * SSTRIDE;
  float s0 = 0.f, s1 = 0.f;
#pragma unroll 8
  for (int blk = 0; blk < nb; blk += 2) {
    s0 += src[(size_t)blk * stride];
    s1 += src[(size_t)(blk + 1) * stride];
  }
  stats[(size_t)comp * SSTRIDE + cell] = s0 + s1;
}

// ---------------------------------------------------------------------------
// Kernel 2: params from global stats (fallback path only now).
// ---------------------------------------------------------------------------
__global__ __launch_bounds__(64) void gmm_params(const float* __restrict__ stats,
                                                 float* __restrict__ params) {
  __shared__ float Xl[32 * 33];
  __shared__ float mul[32];

  const int t = threadIdx.x;
  const int i = t & 31;
  const int comp = blockIdx.x;
  const float* sg = stats + (size_t)comp * SSTRIDE;

  const float w = sg[1056];
  const float invw = 1.f / (w + EPS_);
  const float mu_i = sg[1024 + i] * invw;

  float a[32];
#pragma unroll
  for (int j4 = 0; j4 < 8; ++j4) {
    const float4 v = *(const float4*)(sg + i * 32 + 4 * j4);
    a[4 * j4 + 0] = v.x;
    a[4 * j4 + 1] = v.y;
    a[4 * j4 + 2] = v.z;
    a[4 * j4 + 3] = v.w;
  }
#pragma unroll
  for (int j = 0; j < 32; ++j) {
    const float muj = sg[1024 + j] * invw;
    float v = fmaf(a[j], invw, -mu_i * muj);
    v = (j == i) ? v + COVREG_ : v;
    a[j] = v;
  }

  float ldet = 0.f;
  float rd[32];
#pragma unroll
  for (int j = 0; j < 32; ++j) {
    const float diag = __shfl(a[j], j);
    ldet += logf(diag);
    const float rinv = rsqrtf(diag);
    rd[j] = rinv;
    const float lij = a[j] * rinv;
    a[j] = (i >= j) ? lij : a[j];
#pragma unroll
    for (int m = j + 1; m < 32; ++m) {
      const float Lmj = __shfl(lij, m);
      a[m] = (i >= m) ? fmaf(-lij, Lmj, a[m]) : a[m];
    }
  }

  float x[32];
#pragma unroll
  for (int m = 0; m < 32; ++m) {
    float s = (m == i) ? 1.f : 0.f;
#pragma unroll
    for (int r = 0; r < m; ++r) {
      const float Lmr = __shfl(a[r], m);
      s = fmaf(-Lmr, x[r], s);
    }
    x[m] = s * rd[m];
  }

  if (t < 32) {
#pragma unroll
    for (int m = 0; m < 32; ++m) Xl[m * 33 + i] = x[m];
    mul[i] = mu_i;
  }
  __syncthreads();

  float* pg = params + (size_t)comp * PSTRIDE;
  for (int r = 0; r < 32; ++r) {
    const int L4 = 4 * ((r >> 2) + 1);
    if (t < L4) pg[XOFF_[r] + t] = (t <= r) ? Xl[r * 33 + t] : 0.f;
  }
  {
    __half* xh = (__half*)(pg + 612);
#pragma unroll
    for (int th = 0; th < 2; ++th) {
      const int row = th * 16 + (t & 15);
      const int k0 = (t >> 4) * 8;
#pragma unroll
      for (int j = 0; j < 8; ++j) {
        const int k = k0 + j;
        const float v = (k <= row) ? Xl[row * 33 + k] : 0.f;
        xh[(th * 64 + t) * 8 + j] = __float2half(v);
      }
    }
  }
  if (t < 32) {
    float z = 0.f;
    for (int j = 0; j <= t; ++j) z += Xl[t * 33 + j] * mul[j];
    pg[576 + t] = z;
  }
  if (t == 0) {
    const int sib = comp & ~3;
    float wsum = 0.f;
    for (int s2 = 0; s2 < 4; ++s2)
      wsum += stats[(size_t)(sib + s2) * SSTRIDE + 1056];
    const float pi = (w + EPS_) / (wsum + SS * EPS_);
    pg[608] = logf(pi) - 0.5f * (CC * LOG2PI_C + ldet);
  }
}

// ---------------------------------------------------------------------------
// Kernel 3b: final E-step (unchanged from R23).
// ---------------------------------------------------------------------------
template <int TILES>
__global__ __launch_bounds__(256, 2) void gmm_estep_final4(
    const float* __restrict__ feat, const float* __restrict__ params,
    float* __restrict__ out) {
  __shared__ __align__(16) _Float16 fTd[2 * 64 * 56];
  __shared__ int4 xlds4[2048];
  __shared__ float zlds[16 * 32];  // -z
  __shared__ float c0lds[16];

  const int t = threadIdx.x;
  const int b = blockIdx.y;
  const int blk0 = blockIdx.x * (TILES * 64);
  const int w = t >> 6;
  const int l = t & 63;
  const int row16 = l & 15;
  const int kg = l >> 4;

  for (int idx = t; idx < 2048; idx += 256) {
    const int c = idx >> 7, chunk = idx & 127;
    xlds4[idx] = *(const int4*)((const char*)(params +
                                              (size_t)(b * 16 + c) * PSTRIDE +
                                              612) +
                                chunk * 16);
  }
  for (int idx = t; idx < 16 * 32; idx += 256) {
    zlds[idx] =
        -params[(size_t)(b * 16 + (idx >> 5)) * PSTRIDE + 576 + (idx & 31)];
  }
  if (t < 16) c0lds[t] = params[(size_t)(b * 16 + t) * PSTRIDE + 608];

  const _Float16* xl = (const _Float16*)xlds4;
  const int cload = t >> 4;
  const int i4 = (t & 15) * 4;

  float4 pv0 = *(const float4*)(feat + ((size_t)b * CC + cload) * NN + blk0 + i4);
  float4 pv1 =
      *(const float4*)(feat + ((size_t)b * CC + cload + 16) * NN + blk0 + i4);

  for (int tile = 0; tile < TILES; ++tile) {
    const int base = blk0 + tile * 64;
    const int bs = tile & 1;
    _Float16* fT = &fTd[bs * (64 * 56)];
    {
      fT[(i4 + 0) * 56 + cload] = (_Float16)pv0.x;
      fT[(i4 + 1) * 56 + cload] = (_Float16)pv0.y;
      fT[(i4 + 2) * 56 + cload] = (_Float16)pv0.z;
      fT[(i4 + 3) * 56 + cload] = (_Float16)pv0.w;
      fT[(i4 + 0) * 56 + cload + 16] = (_Float16)pv1.x;
      fT[(i4 + 1) * 56 + cload + 16] = (_Float16)pv1.y;
      fT[(i4 + 2) * 56 + cload + 16] = (_Float16)pv1.z;
      fT[(i4 + 3) * 56 + cload + 16] = (_Float16)pv1.w;
    }
    __syncthreads();

    if (tile < TILES - 1) {
      const int nb2 = base + 64;
      pv0 = *(const float4*)(feat + ((size_t)b * CC + cload) * NN + nb2 + i4);
      pv1 = *(const float4*)(feat + ((size_t)b * CC + cload + 16) * NN + nb2 +
                             i4);
    }

    const half8 bfr = *(const half8*)&fT[(w * 16 + row16) * 56 + kg * 8];

    float lp[16];
#pragma unroll
    for (int c = 0; c < 16; ++c) {
      const half8 a0 = *(const half8*)&xl[c * 1024 + (0 * 64 + l) * 8];
      const half8 a1 = *(const half8*)&xl[c * 1024 + (1 * 64 + l) * 8];
      const floatx4 cin0 = *(const floatx4*)&zlds[c * 32 + kg * 4];
      const floatx4 cin1 = *(const floatx4*)&zlds[c * 32 + 16 + kg * 4];
      floatx4 y0 =
          __builtin_amdgcn_mfma_f32_16x16x32_f16(a0, bfr, cin0, 0, 0, 0);
      floatx4 y1 =
          __builtin_amdgcn_mfma_f32_16x16x32_f16(a1, bfr, cin1, 0, 0, 0);
      float q = 0.f;
      q = fmaf(y0[0], y0[0], q);
      q = fmaf(y0[1], y0[1], q);
      q = fmaf(y0[2], y0[2], q);
      q = fmaf(y0[3], y0[3], q);
      q = fmaf(y1[0], y1[0], q);
      q = fmaf(y1[1], y1[1], q);
      q = fmaf(y1[2], y1[2], q);
      q = fmaf(y1[3], y1[3], q);
      q += __shfl_xor(q, 16);
      q += __shfl_xor(q, 32);
      lp[c] = c0lds[c] - 0.5f * q;
    }

    float cll[4];
#pragma unroll
    for (int k = 0; k < 4; ++k) {
      const float m = fmaxf(fmaxf(lp[4 * k + 0], lp[4 * k + 1]),
                            fmaxf(lp[4 * k + 2], lp[4 * k + 3]));
      const float s = expf(lp[4 * k + 0] - m) + expf(lp[4 * k + 1] - m) +
                      expf(lp[4 * k + 2] - m) + expf(lp[4 * k + 3] - m);
      cll[k] = m + logf(s);
    }
    const float m = fmaxf(fmaxf(cll[0], cll[1]), fmaxf(cll[2], cll[3]));
    const float e0 = expf(cll[0] - m), e1 = expf(cll[1] - m);
    const float e2 = expf(cll[2] - m), e3 = expf(cll[3] - m);
    const float inv = 1.f / (e0 + e1 + e2 + e3);
    if (l < 16) {
      const int n = base + w * 16 + l;
      out[((size_t)b * KK + 0) * NN + n] = e0 * inv;
      out[((size_t)b * KK + 1) * NN + n] = e1 * inv;
      out[((size_t)b * KK + 2) * NN + n] = e2 * inv;
      out[((size_t)b * KK + 3) * NN + n] = e3 * inv;
    }
  }
}

// ---------------------------------------------------------------------------
// Atomic fallback path (unchanged).
// ---------------------------------------------------------------------------
template <bool ITER0, bool ATOMIC, int TILES>
__global__ __launch_bounds__(256, 1) void gmm_accum(
    const float* __restrict__ feat, const int* __restrict__ labels,
    const float* __restrict__ resp, float* __restrict__ outbuf) {
  __shared__ float fT[64 * 36];
  __shared__ float resp_lds[64 * 4];
  __shared__ int lab_lds[64];

  const int t = threadIdx.x;
  const int b = blockIdx.y;
  const int blk0 = blockIdx.x * (TILES * 64);

  const int wv = t >> 6;
  const int l = t & 63;
  const int sc = (t >> 4) & 3;
  const int p = t & 15;
  const int a0 = (p >> 2) * 8;
  const int b0 = (p & 3) * 8;

  float acc[8][8];
#pragma unroll
  for (int x = 0; x < 8; ++x)
#pragma unroll
    for (int y = 0; y < 8; ++y) acc[x][y] = 0.f;
  float sx[8] = {0, 0, 0, 0, 0, 0, 0, 0};
  float wacc = 0.f;

  const int cload = t >> 4;
  const int i4 = (t & 15) * 4;

  float4 pf0, pf1;
  float4 presp = make_float4(0, 0, 0, 0);
  int plab = 0;
  {
    const int n0 = blk0;
    pf0 = *(const float4*)(feat + ((size_t)b * CC + cload) * NN + n0 + i4);
    pf1 = *(const float4*)(feat + ((size_t)b * CC + cload + 16) * NN + n0 + i4);
    if (t < 64) {
      plab = labels[b * NN + n0 + t];
      if (!ITER0)
        presp = *(const float4*)(resp + ((size_t)b * NN + n0 + t) * 4);
    }
  }

  for (int tile = 0; tile < TILES; ++tile) {
    fT[(i4 + 0) * 36 + cload] = pf0.x;
    fT[(i4 + 1) * 36 + cload] = pf0.y;
    fT[(i4 + 2) * 36 + cload] = pf0.z;
    fT[(i4 + 3) * 36 + cload] = pf0.w;
    fT[(i4 + 0) * 36 + cload + 16] = pf1.x;
    fT[(i4 + 1) * 36 + cload + 16] = pf1.y;
    fT[(i4 + 2) * 36 + cload + 16] = pf1.z;
    fT[(i4 + 3) * 36 + cload + 16] = pf1.w;
    if (t < 64) {
      lab_lds[t] = plab;
      if (ITER0) {
        const int cmp = (blk0 + tile * 64 + t) & 3;
        resp_lds[t * 4 + 0] = (cmp == 0) ? 1.f : 0.f;
        resp_lds[t * 4 + 1] = (cmp == 1) ? 1.f : 0.f;
        resp_lds[t * 4 + 2] = (cmp == 2) ? 1.f : 0.f;
        resp_lds[t * 4 + 3] = (cmp == 3) ? 1.f : 0.f;
      } else {
        resp_lds[t * 4 + 0] = presp.x;
        resp_lds[t * 4 + 1] = presp.y;
        resp_lds[t * 4 + 2] = presp.z;
        resp_lds[t * 4 + 3] = presp.w;
      }
    }
    __syncthreads();
    if (tile < TILES - 1) {
      const int n0 = blk0 + (tile + 1) * 64;
      pf0 = *(const float4*)(feat + ((size_t)b * CC + cload) * NN + n0 + i4);
      pf1 =
          *(const float4*)(feat + ((size_t)b * CC + cload + 16) * NN + n0 + i4);
      if (t < 64) {
        plab = labels[b * NN + n0 + t];
        if (!ITER0)
          presp = *(const float4*)(resp + ((size_t)b * NN + n0 + t) * 4);
      }
    }

    unsigned long long m = __ballot(lab_lds[l] == wv);
    while (m) {
      const int i = __builtin_ctzll(m);
      m &= m - 1;
      const float rs = resp_lds[i * 4 + sc];
      const float4 ra0 = *(const float4*)&fT[i * 36 + a0];
      const float4 ra1 = *(const float4*)&fT[i * 36 + a0 + 4];
      const float4 rb0 = *(const float4*)&fT[i * 36 + b0];
      const float4 rb1 = *(const float4*)&fT[i * 36 + b0 + 4];
      const float ra[8] = {ra0.x, ra0.y, ra0.z, ra0.w,
                           ra1.x, ra1.y, ra1.z, ra1.w};
      const float rb[8] = {rb0.x, rb0.y, rb0.z, rb0.w,
                           rb1.x, rb1.y, rb1.z, rb1.w};
#pragma unroll
      for (int x = 0; x < 8; ++x) {
        const float v = rs * ra[x];
#pragma unroll
        for (int y = 0; y < 8; ++y) acc[x][y] = fmaf(v, rb[y], acc[x][y]);
      }
#pragma unroll
      for (int y = 0; y < 8; ++y) sx[y] = fmaf(rs, rb[y], sx[y]);
      wacc += rs;
    }
    __syncthreads();
  }

  if (ATOMIC) {
    float* sg = outbuf + ((size_t)(b * KK + wv) * SS + sc) * SSTRIDE;
#pragma unroll
    for (int x = 0; x < 8; ++x)
#pragma unroll
      for (int y = 0; y < 8; ++y)
        atomicAdd(sg + (a0 + x) * 32 + b0 + y, acc[x][y]);
    if (p < 4) {
#pragma unroll
      for (int y = 0; y < 8; ++y) atomicAdd(sg + 1024 + b0 + y, sx[y]);
    }
    if (p == 0) atomicAdd(sg + 1056, wacc);
  } else {
    const int nb = NN / (TILES * 64);
    float* sg = outbuf + ((size_t)(b * nb + blockIdx.x) * 16 + (wv * 4 + sc)) *
                             SSTRIDE;
#pragma unroll
    for (int x = 0; x < 8; ++x)
#pragma unroll
      for (int y = 0; y < 8; ++y) sg[(a0 + x) * 32 + b0 + y] = acc[x][y];
    if (p < 4) {
#pragma unroll
      for (int y = 0; y < 8; ++y) sg[1024 + b0 + y] = sx[y];
    }
    if (p == 0) sg[1056] = wacc;
  }
}

template <int TILES>
__global__ __launch_bounds__(256, 2) void gmm_estep_own4(
    const float* __restrict__ feat, const int* __restrict__ labels,
    const float* __restrict__ params, float* __restrict__ resp) {
  __shared__ float fT[64 * 36];
  __shared__ int4 xlds4[2048];
  __shared__ float zlds[16 * 32];
  __shared__ float c0lds[16];
  __shared__ int lab_lds[64];

  const int t = threadIdx.x;
  const int b = blockIdx.y;
  const int blk0 = blockIdx.x * (TILES * 64);
  const int w = t >> 6;
  const int l = t & 63;
  const int row16 = l & 15;
  const int kg = l >> 4;

  for (int idx = t; idx < 2048; idx += 256) {
    const int c = idx >> 7, chunk = idx & 127;
    xlds4[idx] = *(const int4*)((const char*)(params +
                                              (size_t)(b * 16 + c) * PSTRIDE +
                                              612) +
                                chunk * 16);
  }
  for (int idx = t; idx < 16 * 32; idx += 256) {
    zlds[idx] =
        -params[(size_t)(b * 16 + (idx >> 5)) * PSTRIDE + 576 + (idx & 31)];
  }
  if (t < 16) c0lds[t] = params[(size_t)(b * 16 + t) * PSTRIDE + 608];

  const _Float16* xl = (const _Float16*)xlds4;
  const int cload = t >> 4;
  const int i4 = (t & 15) * 4;

  for (int tile = 0; tile < TILES; ++tile) {
    const int base = blk0 + tile * 64;
    {
      const float4 v0 =
          *(const float4*)(feat + ((size_t)b * CC + cload) * NN + base + i4);
      const float4 v1 = *(const float4*)(feat +
                                         ((size_t)b * CC + cload + 16) * NN +
                                         base + i4);
      fT[(i4 + 0) * 36 + cload] = v0.x;
      fT[(i4 + 1) * 36 + cload] = v0.y;
      fT[(i4 + 2) * 36 + cload] = v0.z;
      fT[(i4 + 3) * 36 + cload] = v0.w;
      fT[(i4 + 0) * 36 + cload + 16] = v1.x;
      fT[(i4 + 1) * 36 + cload + 16] = v1.y;
      fT[(i4 + 2) * 36 + cload + 16] = v1.z;
      fT[(i4 + 3) * 36 + cload + 16] = v1.w;
      if (t < 64) lab_lds[t] = labels[b * NN + base + t];
    }
    __syncthreads();

    const int eoff = (w * 16 + row16) * 36 + kg * 8;
    const float4 fv0 = *(const float4*)&fT[eoff];
    const float4 fv1 = *(const float4*)&fT[eoff + 4];
    half8 bfr;
    bfr[0] = (_Float16)fv0.x;
    bfr[1] = (_Float16)fv0.y;
    bfr[2] = (_Float16)fv0.z;
    bfr[3] = (_Float16)fv0.w;
    bfr[4] = (_Float16)fv1.x;
    bfr[5] = (_Float16)fv1.y;
    bfr[6] = (_Float16)fv1.z;
    bfr[7] = (_Float16)fv1.w;

    const int lab = lab_lds[w * 16 + row16];

    float lp0 = 0.f, lp1 = 0.f, lp2 = 0.f, lp3 = 0.f;
#pragma unroll
    for (int c = 0; c < 16; ++c) {
      const half8 a0 = *(const half8*)&xl[c * 1024 + (0 * 64 + l) * 8];
      const half8 a1 = *(const half8*)&xl[c * 1024 + (1 * 64 + l) * 8];
      const floatx4 cin0 = *(const floatx4*)&zlds[c * 32 + kg * 4];
      const floatx4 cin1 = *(const floatx4*)&zlds[c * 32 + 16 + kg * 4];
      floatx4 y0 =
          __builtin_amdgcn_mfma_f32_16x16x32_f16(a0, bfr, cin0, 0, 0, 0);
      floatx4 y1 =
          __builtin_amdgcn_mfma_f32_16x16x32_f16(a1, bfr, cin1, 0, 0, 0);
      float q = 0.f;
      q = fmaf(y0[0], y0[0], q);
      q = fmaf(y0[1], y0[1], q);
      q = fmaf(y0[2], y0[2], q);
      q = fmaf(y0[3], y0[3], q);
      q = fmaf(y1[0], y1[0], q);
      q = fmaf(y1[1], y1[1], q);
      q = fmaf(y1[2], y1[2], q);
      q = fmaf(y1[3], y1[3], q);
      q += __shfl_xor(q, 16);
      q += __shfl_xor(q, 32);
      const float lp = c0lds[c] - 0.5f * q;
      const bool own = (c >> 2) == lab;
      const int s = c & 3;
      lp0 = (own && s == 0) ? lp : lp0;
      lp1 = (own && s == 1) ? lp : lp1;
      lp2 = (own && s == 2) ? lp : lp2;
      lp3 = (own && s == 3) ? lp : lp3;
    }

    const float m = fmaxf(fmaxf(lp0, lp1), fmaxf(lp2, lp3));
    const float e0 = expf(lp0 - m), e1 = expf(lp1 - m);
    const float e2 = expf(lp2 - m), e3 = expf(lp3 - m);
    const float inv = 1.f / (e0 + e1 + e2 + e3);
    if (l < 16) {
      *(float4*)(resp + ((size_t)b * NN + base + w * 16 + l) * 4) =
          make_float4(e0 * inv, e1 * inv, e2 * inv, e3 * inv);
    }
    __syncthreads();
  }
}

// ---------------------------------------------------------------------------
extern "C" void kernel_launch(void* const* d_in, const int* in_sizes, int n_in,
                              void* d_out, int out_size, void* d_ws,
                              size_t ws_size, hipStream_t stream) {
  const float* feat = (const float*)d_in[0];
  const int* labels = (const int*)d_in[1];
  float* out = (float*)d_out;

  float* stats = (float*)d_ws;
  float* params = stats + (size_t)NCOMP * SSTRIDE;
  float* resp_ws = params + (size_t)NCOMP * PSTRIDE;
  float* partials = resp_ws + (size_t)BB * NN * 4;

  const size_t base_need_f =
      (size_t)NCOMP * SSTRIDE + (size_t)NCOMP * PSTRIDE + (size_t)BB * NN * 4;
  const size_t need128 =
      (base_need_f + (size_t)BB * NB * 16 * SSTRIDE) * sizeof(float);
  const bool have_resp = ws_size >= base_need_f * sizeof(float);
  float* resp = have_resp ? resp_ws : out;

  if (ws_size >= need128) {
    gmm_accum_mfma<true, 16>
        <<<dim3(NB, BB), 256, 0, stream>>>(feat, labels, out, partials);
    gmm_reduce_params<<<NCOMP, 256, 0, stream>>>(partials, params, NB);
    for (int it = 1; it < 3; ++it) {
      gmm_fused<8>
          <<<dim3(NB, BB), 256, 0, stream>>>(feat, labels, params, partials);
      gmm_reduce_params<<<NCOMP, 256, 0, stream>>>(partials, params, NB);
    }
    gmm_estep_final4<8><<<dim3(NN / 512, BB), 256, 0, stream>>>(feat, params,
                                                                out);
  } else {
    for (int it = 0; it < 3; ++it) {
      hipMemsetAsync(stats, 0, (size_t)NCOMP * SSTRIDE * sizeof(float), stream);
      if (it == 0)
        gmm_accum<true, true, 16>
            <<<dim3(64, BB), 256, 0, stream>>>(feat, labels, resp, stats);
      else
        gmm_accum<false, true, 16>
            <<<dim3(64, BB), 256, 0, stream>>>(feat, labels, resp, stats);
      gmm_params<<<NCOMP, 64, 0, stream>>>(stats, params);
      if (it < 2)
        gmm_estep_own4<8><<<dim3(NN / 512, BB), 256, 0, stream>>>(feat, labels,
                                                                  params, resp);
      else
        gmm_estep_final4<8><<<dim3(NN / 512, BB), 256, 0, stream>>>(
            feat, params, out);
    }
  }
}

// Round 25
// 252.064 us; speedup vs baseline: 1.3642x; 1.3642x over previous
//
#include <hip/hip_runtime.h>
#include <hip/hip_fp16.h>
#include <math.h>

#define BB 4
#define CC 32
#define KK 4
#define SS 4
#define NN 65536

constexpr int NCOMP = 64;
constexpr int SSTRIDE = 1088;
constexpr int PSTRIDE = 1128;
constexpr int NB = 128;
constexpr float EPS_ = 1e-6f;
constexpr float COVREG_ = 1e-4f;
constexpr float LOG2PI_C = 1.8378770664093453f;

__device__ constexpr int XOFF_[32] = {
    0,   4,   8,   12,  16,  24,  32,  40,  48,  60,  72,
    84,  96,  112, 128, 144, 160, 180, 200, 220, 240, 264,
    288, 312, 336, 364, 392, 420, 448, 480, 512, 544};

typedef _Float16 half8 __attribute__((ext_vector_type(8)));
typedef _Float16 half4 __attribute__((ext_vector_type(4)));
typedef float floatx4 __attribute__((ext_vector_type(4)));

// ---------------------------------------------------------------------------
// Kernel 1: iter-0 stats via MFMA (unchanged).
// ---------------------------------------------------------------------------
template <bool ITER0, int CHUNKS>
__global__ __launch_bounds__(256, 2) void gmm_accum_mfma(
    const float* __restrict__ feat, const int* __restrict__ labels,
    const float* __restrict__ resp, float* __restrict__ partials) {
  __shared__ __align__(16) _Float16 fC[32 * 48];
  __shared__ __align__(16) _Float16 respH[4][32];
  __shared__ __align__(16) _Float16 maskH[4][32];

  const int t = threadIdx.x;
  const int b = blockIdx.y;
  const int blk0 = blockIdx.x * (CHUNKS * 32);
  const int k = t >> 6;
  const int l = t & 63;
  const int row16 = l & 15;
  const int kg = l >> 4;

  floatx4 acc[4][7];
#pragma unroll
  for (int s = 0; s < 4; ++s)
#pragma unroll
    for (int j = 0; j < 7; ++j) acc[s][j] = (floatx4){0.f, 0.f, 0.f, 0.f};

  const int cstage = t >> 3;
  const int n4 = (t & 7) * 4;

  float4 pf;
  float4 presp = make_float4(0, 0, 0, 0);
  int plab = 0;
  pf = *(const float4*)(feat + ((size_t)b * CC + cstage) * NN + blk0 + n4);
  if (t < 32) {
    plab = labels[b * NN + blk0 + t];
    if (!ITER0) presp = *(const float4*)(resp + ((size_t)b * NN + blk0 + t) * 4);
  }

  const half8 hz = {0, 0, 0, 0, 0, 0, 0, 0};

  for (int chunk = 0; chunk < CHUNKS; ++chunk) {
    {
      half4 hv;
      hv[0] = (_Float16)pf.x;
      hv[1] = (_Float16)pf.y;
      hv[2] = (_Float16)pf.z;
      hv[3] = (_Float16)pf.w;
      *(half4*)&fC[cstage * 48 + n4] = hv;
    }
    if (t < 32) {
      if (ITER0) {
        const int cmp = (blk0 + chunk * 32 + t) & 3;
        respH[0][t] = (cmp == 0) ? (_Float16)1 : (_Float16)0;
        respH[1][t] = (cmp == 1) ? (_Float16)1 : (_Float16)0;
        respH[2][t] = (cmp == 2) ? (_Float16)1 : (_Float16)0;
        respH[3][t] = (cmp == 3) ? (_Float16)1 : (_Float16)0;
      } else {
        respH[0][t] = (_Float16)presp.x;
        respH[1][t] = (_Float16)presp.y;
        respH[2][t] = (_Float16)presp.z;
        respH[3][t] = (_Float16)presp.w;
      }
      maskH[0][t] = (plab == 0) ? (_Float16)1 : (_Float16)0;
      maskH[1][t] = (plab == 1) ? (_Float16)1 : (_Float16)0;
      maskH[2][t] = (plab == 2) ? (_Float16)1 : (_Float16)0;
      maskH[3][t] = (plab == 3) ? (_Float16)1 : (_Float16)0;
    }
    __syncthreads();

    if (chunk < CHUNKS - 1) {
      const int n0n = blk0 + (chunk + 1) * 32;
      pf = *(const float4*)(feat + ((size_t)b * CC + cstage) * NN + n0n + n4);
      if (t < 32) {
        plab = labels[b * NN + n0n + t];
        if (!ITER0)
          presp = *(const float4*)(resp + ((size_t)b * NN + n0n + t) * 4);
      }
    }

    const half8 ff0 = *(const half8*)&fC[row16 * 48 + kg * 8];
    const half8 ff1 = *(const half8*)&fC[(row16 + 16) * 48 + kg * 8];

    const half8 mh = *(const half8*)&maskH[k][kg * 8];
    const half8 H0 = ff0 * mh;
    const half8 H1 = ff1 * mh;
    const half8 agB = (row16 == 0) ? mh : hz;

#pragma unroll
    for (int s = 0; s < 4; ++s) {
      const half8 rh = *(const half8*)&respH[s][kg * 8];
      const half8 G0 = ff0 * rh;
      const half8 G1 = ff1 * rh;
      const half8 agA = (row16 == 0) ? rh : hz;
      acc[s][0] =
          __builtin_amdgcn_mfma_f32_16x16x32_f16(G0, H0, acc[s][0], 0, 0, 0);
      acc[s][1] =
          __builtin_amdgcn_mfma_f32_16x16x32_f16(G0, H1, acc[s][1], 0, 0, 0);
      acc[s][2] =
          __builtin_amdgcn_mfma_f32_16x16x32_f16(G1, H0, acc[s][2], 0, 0, 0);
      acc[s][3] =
          __builtin_amdgcn_mfma_f32_16x16x32_f16(G1, H1, acc[s][3], 0, 0, 0);
      acc[s][4] =
          __builtin_amdgcn_mfma_f32_16x16x32_f16(G0, agB, acc[s][4], 0, 0, 0);
      acc[s][5] =
          __builtin_amdgcn_mfma_f32_16x16x32_f16(G1, agB, acc[s][5], 0, 0, 0);
      acc[s][6] =
          __builtin_amdgcn_mfma_f32_16x16x32_f16(agA, agB, acc[s][6], 0, 0, 0);
    }
    __syncthreads();
  }

#pragma unroll
  for (int s = 0; s < 4; ++s) {
    float* sg = partials + ((size_t)(b * gridDim.x + blockIdx.x) * 16 +
                            (k * 4 + s)) *
                               SSTRIDE;
    const int dr = kg * 4;
#pragma unroll
    for (int r = 0; r < 4; ++r) {
      sg[(dr + r) * 32 + row16] = acc[s][0][r];
      sg[(dr + r) * 32 + 16 + row16] = acc[s][1][r];
      sg[(16 + dr + r) * 32 + row16] = acc[s][2][r];
      sg[(16 + dr + r) * 32 + 16 + row16] = acc[s][3][r];
    }
    if (row16 == 0) {
#pragma unroll
      for (int r = 0; r < 4; ++r) {
        sg[1024 + dr + r] = acc[s][4][r];
        sg[1024 + 16 + dr + r] = acc[s][5][r];
      }
    }
    if (l == 0) sg[1056] = acc[s][6][0];
  }
}

// ---------------------------------------------------------------------------
// Kernel F: fused E+M with register prefetch + LDS double-buffering
// (R23-proven).
// ---------------------------------------------------------------------------
template <int TILES>
__global__ __launch_bounds__(256, 2) void gmm_fused(
    const float* __restrict__ feat, const int* __restrict__ labels,
    const float* __restrict__ params, float* __restrict__ partials) {
  __shared__ __align__(16) _Float16 fTd[2 * 64 * 56];
  __shared__ __align__(16) _Float16 fCd[2 * 32 * 72];
  __shared__ int4 xlds4[2048];
  __shared__ float zlds[16 * 32];  // -z
  __shared__ float c0lds[16];
  __shared__ int lab_lds[2][64];
  __shared__ __align__(16) _Float16 respHd[2][4][64];
  __shared__ __align__(16) _Float16 maskHd[2][4][64];

  const int t = threadIdx.x;
  const int b = blockIdx.y;
  const int blk0 = blockIdx.x * (TILES * 64);
  const int w = t >> 6;
  const int l = t & 63;
  const int row16 = l & 15;
  const int kg = l >> 4;

  for (int idx = t; idx < 2048; idx += 256) {
    const int c = idx >> 7, chunk = idx & 127;
    xlds4[idx] = *(const int4*)((const char*)(params +
                                              (size_t)(b * 16 + c) * PSTRIDE +
                                              612) +
                                chunk * 16);
  }
  for (int idx = t; idx < 16 * 32; idx += 256) {
    zlds[idx] =
        -params[(size_t)(b * 16 + (idx >> 5)) * PSTRIDE + 576 + (idx & 31)];
  }
  if (t < 16) c0lds[t] = params[(size_t)(b * 16 + t) * PSTRIDE + 608];

  const _Float16* xl = (const _Float16*)xlds4;
  const int cload = t >> 4;
  const int i4 = (t & 15) * 4;
  const half8 hz = {0, 0, 0, 0, 0, 0, 0, 0};

  floatx4 acc[4][7];
#pragma unroll
  for (int s = 0; s < 4; ++s)
#pragma unroll
    for (int j = 0; j < 7; ++j) acc[s][j] = (floatx4){0.f, 0.f, 0.f, 0.f};

  float4 pv0 = *(const float4*)(feat + ((size_t)b * CC + cload) * NN + blk0 + i4);
  float4 pv1 =
      *(const float4*)(feat + ((size_t)b * CC + cload + 16) * NN + blk0 + i4);
  int plab = (t < 64) ? labels[b * NN + blk0 + t] : 0;

  for (int tile = 0; tile < TILES; ++tile) {
    const int base = blk0 + tile * 64;
    const int bs = tile & 1;
    _Float16* fT = &fTd[bs * (64 * 56)];
    _Float16* fC = &fCd[bs * (32 * 72)];

    {
      const _Float16 h0x = (_Float16)pv0.x, h0y = (_Float16)pv0.y;
      const _Float16 h0z = (_Float16)pv0.z, h0w = (_Float16)pv0.w;
      const _Float16 h1x = (_Float16)pv1.x, h1y = (_Float16)pv1.y;
      const _Float16 h1z = (_Float16)pv1.z, h1w = (_Float16)pv1.w;
      fT[(i4 + 0) * 56 + cload] = h0x;
      fT[(i4 + 1) * 56 + cload] = h0y;
      fT[(i4 + 2) * 56 + cload] = h0z;
      fT[(i4 + 3) * 56 + cload] = h0w;
      fT[(i4 + 0) * 56 + cload + 16] = h1x;
      fT[(i4 + 1) * 56 + cload + 16] = h1y;
      fT[(i4 + 2) * 56 + cload + 16] = h1z;
      fT[(i4 + 3) * 56 + cload + 16] = h1w;
      half4 a, c2;
      a[0] = h0x; a[1] = h0y; a[2] = h0z; a[3] = h0w;
      c2[0] = h1x; c2[1] = h1y; c2[2] = h1z; c2[3] = h1w;
      *(half4*)&fC[cload * 72 + i4] = a;
      *(half4*)&fC[(cload + 16) * 72 + i4] = c2;
      if (t < 64) lab_lds[bs][t] = plab;
    }
    __syncthreads();  // sync1

    if (tile < TILES - 1) {
      const int nb2 = base + 64;
      pv0 = *(const float4*)(feat + ((size_t)b * CC + cload) * NN + nb2 + i4);
      pv1 = *(const float4*)(feat + ((size_t)b * CC + cload + 16) * NN + nb2 +
                             i4);
      if (t < 64) plab = labels[b * NN + nb2 + t];
    }

    // ---- E-core ----
    const half8 bfr = *(const half8*)&fT[(w * 16 + row16) * 56 + kg * 8];
    const int lab = lab_lds[bs][w * 16 + row16];

    float lp0 = 0.f, lp1 = 0.f, lp2 = 0.f, lp3 = 0.f;
#pragma unroll
    for (int c = 0; c < 16; ++c) {
      const half8 a0 = *(const half8*)&xl[c * 1024 + (0 * 64 + l) * 8];
      const half8 a1 = *(const half8*)&xl[c * 1024 + (1 * 64 + l) * 8];
      const floatx4 cin0 = *(const floatx4*)&zlds[c * 32 + kg * 4];
      const floatx4 cin1 = *(const floatx4*)&zlds[c * 32 + 16 + kg * 4];
      floatx4 y0 =
          __builtin_amdgcn_mfma_f32_16x16x32_f16(a0, bfr, cin0, 0, 0, 0);
      floatx4 y1 =
          __builtin_amdgcn_mfma_f32_16x16x32_f16(a1, bfr, cin1, 0, 0, 0);
      float q = 0.f;
      q = fmaf(y0[0], y0[0], q);
      q = fmaf(y0[1], y0[1], q);
      q = fmaf(y0[2], y0[2], q);
      q = fmaf(y0[3], y0[3], q);
      q = fmaf(y1[0], y1[0], q);
      q = fmaf(y1[1], y1[1], q);
      q = fmaf(y1[2], y1[2], q);
      q = fmaf(y1[3], y1[3], q);
      q += __shfl_xor(q, 16);
      q += __shfl_xor(q, 32);
      const float lp = c0lds[c] - 0.5f * q;
      const bool own = (c >> 2) == lab;
      const int s = c & 3;
      lp0 = (own && s == 0) ? lp : lp0;
      lp1 = (own && s == 1) ? lp : lp1;
      lp2 = (own && s == 2) ? lp : lp2;
      lp3 = (own && s == 3) ? lp : lp3;
    }

    {
      const float m = fmaxf(fmaxf(lp0, lp1), fmaxf(lp2, lp3));
      const float e0 = expf(lp0 - m), e1 = expf(lp1 - m);
      const float e2 = expf(lp2 - m), e3 = expf(lp3 - m);
      const float inv = 1.f / (e0 + e1 + e2 + e3);
      if (l < 16) {
        const int e = w * 16 + l;
        respHd[bs][0][e] = (_Float16)(e0 * inv);
        respHd[bs][1][e] = (_Float16)(e1 * inv);
        respHd[bs][2][e] = (_Float16)(e2 * inv);
        respHd[bs][3][e] = (_Float16)(e3 * inv);
      }
      if (t < 64) {
        const int lb2 = lab_lds[bs][t];
        maskHd[bs][0][t] = (lb2 == 0) ? (_Float16)1 : (_Float16)0;
        maskHd[bs][1][t] = (lb2 == 1) ? (_Float16)1 : (_Float16)0;
        maskHd[bs][2][t] = (lb2 == 2) ? (_Float16)1 : (_Float16)0;
        maskHd[bs][3][t] = (lb2 == 3) ? (_Float16)1 : (_Float16)0;
      }
    }
    __syncthreads();  // sync2

    // ---- M-core ----
#pragma unroll
    for (int h = 0; h < 2; ++h) {
      const int eb = h * 32;
      const half8 ff0 = *(const half8*)&fC[row16 * 72 + eb + kg * 8];
      const half8 ff1 = *(const half8*)&fC[(row16 + 16) * 72 + eb + kg * 8];

      const half8 mh = *(const half8*)&maskHd[bs][w][eb + kg * 8];
      const half8 H0 = ff0 * mh;
      const half8 H1 = ff1 * mh;
      const half8 agB = (row16 == 0) ? mh : hz;

#pragma unroll
      for (int s = 0; s < 4; ++s) {
        const half8 rh = *(const half8*)&respHd[bs][s][eb + kg * 8];
        const half8 G0 = ff0 * rh;
        const half8 G1 = ff1 * rh;
        const half8 agA = (row16 == 0) ? rh : hz;
        acc[s][0] =
            __builtin_amdgcn_mfma_f32_16x16x32_f16(G0, H0, acc[s][0], 0, 0, 0);
        acc[s][1] =
            __builtin_amdgcn_mfma_f32_16x16x32_f16(G0, H1, acc[s][1], 0, 0, 0);
        acc[s][2] =
            __builtin_amdgcn_mfma_f32_16x16x32_f16(G1, H0, acc[s][2], 0, 0, 0);
        acc[s][3] =
            __builtin_amdgcn_mfma_f32_16x16x32_f16(G1, H1, acc[s][3], 0, 0, 0);
        acc[s][4] =
            __builtin_amdgcn_mfma_f32_16x16x32_f16(G0, agB, acc[s][4], 0, 0, 0);
        acc[s][5] =
            __builtin_amdgcn_mfma_f32_16x16x32_f16(G1, agB, acc[s][5], 0, 0, 0);
        acc[s][6] = __builtin_amdgcn_mfma_f32_16x16x32_f16(agA, agB, acc[s][6],
                                                           0, 0, 0);
      }
    }
  }

#pragma unroll
  for (int s = 0; s < 4; ++s) {
    float* sg = partials + ((size_t)(b * gridDim.x + blockIdx.x) * 16 +
                            (w * 4 + s)) *
                               SSTRIDE;
    const int dr = kg * 4;
#pragma unroll
    for (int r = 0; r < 4; ++r) {
      sg[(dr + r) * 32 + row16] = acc[s][0][r];
      sg[(dr + r) * 32 + 16 + row16] = acc[s][1][r];
      sg[(16 + dr + r) * 32 + row16] = acc[s][2][r];
      sg[(16 + dr + r) * 32 + 16 + row16] = acc[s][3][r];
    }
    if (row16 == 0) {
#pragma unroll
      for (int r = 0; r < 4; ++r) {
        sg[1024 + dr + r] = acc[s][4][r];
        sg[1024 + 16 + dr + r] = acc[s][5][r];
      }
    }
    if (l == 0) sg[1056] = acc[s][6][0];
  }
}

// ---------------------------------------------------------------------------
// Kernel 1b: reduce block-partials -> stats (R23 parallel version: 265
// blocks, one thread per (comp,cell) — the R24 64-block merge regressed).
// ---------------------------------------------------------------------------
__global__ __launch_bounds__(256) void gmm_reduce(const float* __restrict__ part,
                                                  float* __restrict__ stats,
                                                  int nb) {
  const int idx = blockIdx.x * 256 + threadIdx.x;
  if (idx >= NCOMP * 1057) return;
  const int comp = idx / 1057;
  const int cell = idx - comp * 1057;
  const int b = comp >> 4, cl = comp & 15;
  const float* src = part + ((size_t)(b * nb) * 16 + cl) * SSTRIDE + cell;
  const size_t stride = (size_t)16 * SSTRIDE;
  float s0 = 0.f, s1 = 0.f;
#pragma unroll 8
  for (int blk = 0; blk < nb; blk += 2) {
    s0 += src[(size_t)blk * stride];
    s1 += src[(size_t)(blk + 1) * stride];
  }
  stats[(size_t)comp * SSTRIDE + cell] = s0 + s1;
}

// ---------------------------------------------------------------------------
// Kernel 2: params via register/shfl Cholesky; inversion dot-products now
// use 4 interleaved partial sums (breaks the 31-deep serial fma chain per
// row; FP reassociation within ample error margin).
// ---------------------------------------------------------------------------
__global__ __launch_bounds__(64) void gmm_params(const float* __restrict__ stats,
                                                 float* __restrict__ params) {
  __shared__ float Xl[32 * 33];
  __shared__ float mul[32];

  const int t = threadIdx.x;
  const int i = t & 31;
  const int comp = blockIdx.x;
  const float* sg = stats + (size_t)comp * SSTRIDE;

  const float w = sg[1056];
  const float invw = 1.f / (w + EPS_);
  const float mu_i = sg[1024 + i] * invw;

  float a[32];
#pragma unroll
  for (int j4 = 0; j4 < 8; ++j4) {
    const float4 v = *(const float4*)(sg + i * 32 + 4 * j4);
    a[4 * j4 + 0] = v.x;
    a[4 * j4 + 1] = v.y;
    a[4 * j4 + 2] = v.z;
    a[4 * j4 + 3] = v.w;
  }
#pragma unroll
  for (int j = 0; j < 32; ++j) {
    const float muj = sg[1024 + j] * invw;
    float v = fmaf(a[j], invw, -mu_i * muj);
    v = (j == i) ? v + COVREG_ : v;
    a[j] = v;
  }

  float ldet = 0.f;
  float rd[32];
#pragma unroll
  for (int j = 0; j < 32; ++j) {
    const float diag = __shfl(a[j], j);
    ldet += logf(diag);
    const float rinv = rsqrtf(diag);
    rd[j] = rinv;
    const float lij = a[j] * rinv;
    a[j] = (i >= j) ? lij : a[j];
#pragma unroll
    for (int m = j + 1; m < 32; ++m) {
      const float Lmj = __shfl(lij, m);
      a[m] = (i >= m) ? fmaf(-lij, Lmj, a[m]) : a[m];
    }
  }

  // inversion with 4-way ILP on the r-chain
  float x[32];
#pragma unroll
  for (int m = 0; m < 32; ++m) {
    float s0 = (m == i) ? 1.f : 0.f, s1 = 0.f, s2 = 0.f, s3 = 0.f;
#pragma unroll
    for (int r = 0; r < m; ++r) {
      const float Lmr = __shfl(a[r], m);
      const float p = -Lmr * x[r];
      if ((r & 3) == 0) s0 += p;
      else if ((r & 3) == 1) s1 += p;
      else if ((r & 3) == 2) s2 += p;
      else s3 += p;
    }
    x[m] = ((s0 + s1) + (s2 + s3)) * rd[m];
  }

  if (t < 32) {
#pragma unroll
    for (int m = 0; m < 32; ++m) Xl[m * 33 + i] = x[m];
    mul[i] = mu_i;
  }
  __syncthreads();

  float* pg = params + (size_t)comp * PSTRIDE;
  for (int r = 0; r < 32; ++r) {
    const int L4 = 4 * ((r >> 2) + 1);
    if (t < L4) pg[XOFF_[r] + t] = (t <= r) ? Xl[r * 33 + t] : 0.f;
  }
  {
    __half* xh = (__half*)(pg + 612);
#pragma unroll
    for (int th = 0; th < 2; ++th) {
      const int row = th * 16 + (t & 15);
      const int k0 = (t >> 4) * 8;
#pragma unroll
      for (int j = 0; j < 8; ++j) {
        const int k = k0 + j;
        const float v = (k <= row) ? Xl[row * 33 + k] : 0.f;
        xh[(th * 64 + t) * 8 + j] = __float2half(v);
      }
    }
  }
  if (t < 32) {
    float z = 0.f;
    for (int j = 0; j <= t; ++j) z += Xl[t * 33 + j] * mul[j];
    pg[576 + t] = z;
  }
  if (t == 0) {
    const int sib = comp & ~3;
    float wsum = 0.f;
    for (int s2 = 0; s2 < 4; ++s2)
      wsum += stats[(size_t)(sib + s2) * SSTRIDE + 1056];
    const float pi = (w + EPS_) / (wsum + SS * EPS_);
    pg[608] = logf(pi) - 0.5f * (CC * LOG2PI_C + ldet);
  }
}

// ---------------------------------------------------------------------------
// Kernel 3b: final E-step (R23-proven: fp16 fT dbuf + prefetch, 1 barrier).
// ---------------------------------------------------------------------------
template <int TILES>
__global__ __launch_bounds__(256, 2) void gmm_estep_final4(
    const float* __restrict__ feat, const float* __restrict__ params,
    float* __restrict__ out) {
  __shared__ __align__(16) _Float16 fTd[2 * 64 * 56];
  __shared__ int4 xlds4[2048];
  __shared__ float zlds[16 * 32];  // -z
  __shared__ float c0lds[16];

  const int t = threadIdx.x;
  const int b = blockIdx.y;
  const int blk0 = blockIdx.x * (TILES * 64);
  const int w = t >> 6;
  const int l = t & 63;
  const int row16 = l & 15;
  const int kg = l >> 4;

  for (int idx = t; idx < 2048; idx += 256) {
    const int c = idx >> 7, chunk = idx & 127;
    xlds4[idx] = *(const int4*)((const char*)(params +
                                              (size_t)(b * 16 + c) * PSTRIDE +
                                              612) +
                                chunk * 16);
  }
  for (int idx = t; idx < 16 * 32; idx += 256) {
    zlds[idx] =
        -params[(size_t)(b * 16 + (idx >> 5)) * PSTRIDE + 576 + (idx & 31)];
  }
  if (t < 16) c0lds[t] = params[(size_t)(b * 16 + t) * PSTRIDE + 608];

  const _Float16* xl = (const _Float16*)xlds4;
  const int cload = t >> 4;
  const int i4 = (t & 15) * 4;

  float4 pv0 = *(const float4*)(feat + ((size_t)b * CC + cload) * NN + blk0 + i4);
  float4 pv1 =
      *(const float4*)(feat + ((size_t)b * CC + cload + 16) * NN + blk0 + i4);

  for (int tile = 0; tile < TILES; ++tile) {
    const int base = blk0 + tile * 64;
    const int bs = tile & 1;
    _Float16* fT = &fTd[bs * (64 * 56)];
    {
      fT[(i4 + 0) * 56 + cload] = (_Float16)pv0.x;
      fT[(i4 + 1) * 56 + cload] = (_Float16)pv0.y;
      fT[(i4 + 2) * 56 + cload] = (_Float16)pv0.z;
      fT[(i4 + 3) * 56 + cload] = (_Float16)pv0.w;
      fT[(i4 + 0) * 56 + cload + 16] = (_Float16)pv1.x;
      fT[(i4 + 1) * 56 + cload + 16] = (_Float16)pv1.y;
      fT[(i4 + 2) * 56 + cload + 16] = (_Float16)pv1.z;
      fT[(i4 + 3) * 56 + cload + 16] = (_Float16)pv1.w;
    }
    __syncthreads();

    if (tile < TILES - 1) {
      const int nb2 = base + 64;
      pv0 = *(const float4*)(feat + ((size_t)b * CC + cload) * NN + nb2 + i4);
      pv1 = *(const float4*)(feat + ((size_t)b * CC + cload + 16) * NN + nb2 +
                             i4);
    }

    const half8 bfr = *(const half8*)&fT[(w * 16 + row16) * 56 + kg * 8];

    float lp[16];
#pragma unroll
    for (int c = 0; c < 16; ++c) {
      const half8 a0 = *(const half8*)&xl[c * 1024 + (0 * 64 + l) * 8];
      const half8 a1 = *(const half8*)&xl[c * 1024 + (1 * 64 + l) * 8];
      const floatx4 cin0 = *(const floatx4*)&zlds[c * 32 + kg * 4];
      const floatx4 cin1 = *(const floatx4*)&zlds[c * 32 + 16 + kg * 4];
      floatx4 y0 =
          __builtin_amdgcn_mfma_f32_16x16x32_f16(a0, bfr, cin0, 0, 0, 0);
      floatx4 y1 =
          __builtin_amdgcn_mfma_f32_16x16x32_f16(a1, bfr, cin1, 0, 0, 0);
      float q = 0.f;
      q = fmaf(y0[0], y0[0], q);
      q = fmaf(y0[1], y0[1], q);
      q = fmaf(y0[2], y0[2], q);
      q = fmaf(y0[3], y0[3], q);
      q = fmaf(y1[0], y1[0], q);
      q = fmaf(y1[1], y1[1], q);
      q = fmaf(y1[2], y1[2], q);
      q = fmaf(y1[3], y1[3], q);
      q += __shfl_xor(q, 16);
      q += __shfl_xor(q, 32);
      lp[c] = c0lds[c] - 0.5f * q;
    }

    float cll[4];
#pragma unroll
    for (int k = 0; k < 4; ++k) {
      const float m = fmaxf(fmaxf(lp[4 * k + 0], lp[4 * k + 1]),
                            fmaxf(lp[4 * k + 2], lp[4 * k + 3]));
      const float s = expf(lp[4 * k + 0] - m) + expf(lp[4 * k + 1] - m) +
                      expf(lp[4 * k + 2] - m) + expf(lp[4 * k + 3] - m);
      cll[k] = m + logf(s);
    }
    const float m = fmaxf(fmaxf(cll[0], cll[1]), fmaxf(cll[2], cll[3]));
    const float e0 = expf(cll[0] - m), e1 = expf(cll[1] - m);
    const float e2 = expf(cll[2] - m), e3 = expf(cll[3] - m);
    const float inv = 1.f / (e0 + e1 + e2 + e3);
    if (l < 16) {
      const int n = base + w * 16 + l;
      out[((size_t)b * KK + 0) * NN + n] = e0 * inv;
      out[((size_t)b * KK + 1) * NN + n] = e1 * inv;
      out[((size_t)b * KK + 2) * NN + n] = e2 * inv;
      out[((size_t)b * KK + 3) * NN + n] = e3 * inv;
    }
  }
}

// ---------------------------------------------------------------------------
// Atomic fallback path (unchanged).
// ---------------------------------------------------------------------------
template <bool ITER0, bool ATOMIC, int TILES>
__global__ __launch_bounds__(256, 1) void gmm_accum(
    const float* __restrict__ feat, const int* __restrict__ labels,
    const float* __restrict__ resp, float* __restrict__ outbuf) {
  __shared__ float fT[64 * 36];
  __shared__ float resp_lds[64 * 4];
  __shared__ int lab_lds[64];

  const int t = threadIdx.x;
  const int b = blockIdx.y;
  const int blk0 = blockIdx.x * (TILES * 64);

  const int wv = t >> 6;
  const int l = t & 63;
  const int sc = (t >> 4) & 3;
  const int p = t & 15;
  const int a0 = (p >> 2) * 8;
  const int b0 = (p & 3) * 8;

  float acc[8][8];
#pragma unroll
  for (int x = 0; x < 8; ++x)
#pragma unroll
    for (int y = 0; y < 8; ++y) acc[x][y] = 0.f;
  float sx[8] = {0, 0, 0, 0, 0, 0, 0, 0};
  float wacc = 0.f;

  const int cload = t >> 4;
  const int i4 = (t & 15) * 4;

  float4 pf0, pf1;
  float4 presp = make_float4(0, 0, 0, 0);
  int plab = 0;
  {
    const int n0 = blk0;
    pf0 = *(const float4*)(feat + ((size_t)b * CC + cload) * NN + n0 + i4);
    pf1 = *(const float4*)(feat + ((size_t)b * CC + cload + 16) * NN + n0 + i4);
    if (t < 64) {
      plab = labels[b * NN + n0 + t];
      if (!ITER0)
        presp = *(const float4*)(resp + ((size_t)b * NN + n0 + t) * 4);
    }
  }

  for (int tile = 0; tile < TILES; ++tile) {
    fT[(i4 + 0) * 36 + cload] = pf0.x;
    fT[(i4 + 1) * 36 + cload] = pf0.y;
    fT[(i4 + 2) * 36 + cload] = pf0.z;
    fT[(i4 + 3) * 36 + cload] = pf0.w;
    fT[(i4 + 0) * 36 + cload + 16] = pf1.x;
    fT[(i4 + 1) * 36 + cload + 16] = pf1.y;
    fT[(i4 + 2) * 36 + cload + 16] = pf1.z;
    fT[(i4 + 3) * 36 + cload + 16] = pf1.w;
    if (t < 64) {
      lab_lds[t] = plab;
      if (ITER0) {
        const int cmp = (blk0 + tile * 64 + t) & 3;
        resp_lds[t * 4 + 0] = (cmp == 0) ? 1.f : 0.f;
        resp_lds[t * 4 + 1] = (cmp == 1) ? 1.f : 0.f;
        resp_lds[t * 4 + 2] = (cmp == 2) ? 1.f : 0.f;
        resp_lds[t * 4 + 3] = (cmp == 3) ? 1.f : 0.f;
      } else {
        resp_lds[t * 4 + 0] = presp.x;
        resp_lds[t * 4 + 1] = presp.y;
        resp_lds[t * 4 + 2] = presp.z;
        resp_lds[t * 4 + 3] = presp.w;
      }
    }
    __syncthreads();
    if (tile < TILES - 1) {
      const int n0 = blk0 + (tile + 1) * 64;
      pf0 = *(const float4*)(feat + ((size_t)b * CC + cload) * NN + n0 + i4);
      pf1 =
          *(const float4*)(feat + ((size_t)b * CC + cload + 16) * NN + n0 + i4);
      if (t < 64) {
        plab = labels[b * NN + n0 + t];
        if (!ITER0)
          presp = *(const float4*)(resp + ((size_t)b * NN + n0 + t) * 4);
      }
    }

    unsigned long long m = __ballot(lab_lds[l] == wv);
    while (m) {
      const int i = __builtin_ctzll(m);
      m &= m - 1;
      const float rs = resp_lds[i * 4 + sc];
      const float4 ra0 = *(const float4*)&fT[i * 36 + a0];
      const float4 ra1 = *(const float4*)&fT[i * 36 + a0 + 4];
      const float4 rb0 = *(const float4*)&fT[i * 36 + b0];
      const float4 rb1 = *(const float4*)&fT[i * 36 + b0 + 4];
      const float ra[8] = {ra0.x, ra0.y, ra0.z, ra0.w,
                           ra1.x, ra1.y, ra1.z, ra1.w};
      const float rb[8] = {rb0.x, rb0.y, rb0.z, rb0.w,
                           rb1.x, rb1.y, rb1.z, rb1.w};
#pragma unroll
      for (int x = 0; x < 8; ++x) {
        const float v = rs * ra[x];
#pragma unroll
        for (int y = 0; y < 8; ++y) acc[x][y] = fmaf(v, rb[y], acc[x][y]);
      }
#pragma unroll
      for (int y = 0; y < 8; ++y) sx[y] = fmaf(rs, rb[y], sx[y]);
      wacc += rs;
    }
    __syncthreads();
  }

  if (ATOMIC) {
    float* sg = outbuf + ((size_t)(b * KK + wv) * SS + sc) * SSTRIDE;
#pragma unroll
    for (int x = 0; x < 8; ++x)
#pragma unroll
      for (int y = 0; y < 8; ++y)
        atomicAdd(sg + (a0 + x) * 32 + b0 + y, acc[x][y]);
    if (p < 4) {
#pragma unroll
      for (int y = 0; y < 8; ++y) atomicAdd(sg + 1024 + b0 + y, sx[y]);
    }
    if (p == 0) atomicAdd(sg + 1056, wacc);
  } else {
    const int nb = NN / (TILES * 64);
    float* sg = outbuf + ((size_t)(b * nb + blockIdx.x) * 16 + (wv * 4 + sc)) *
                             SSTRIDE;
#pragma unroll
    for (int x = 0; x < 8; ++x)
#pragma unroll
      for (int y = 0; y < 8; ++y) sg[(a0 + x) * 32 + b0 + y] = acc[x][y];
    if (p < 4) {
#pragma unroll
      for (int y = 0; y < 8; ++y) sg[1024 + b0 + y] = sx[y];
    }
    if (p == 0) sg[1056] = wacc;
  }
}

template <int TILES>
__global__ __launch_bounds__(256, 2) void gmm_estep_own4(
    const float* __restrict__ feat, const int* __restrict__ labels,
    const float* __restrict__ params, float* __restrict__ resp) {
  __shared__ float fT[64 * 36];
  __shared__ int4 xlds4[2048];
  __shared__ float zlds[16 * 32];
  __shared__ float c0lds[16];
  __shared__ int lab_lds[64];

  const int t = threadIdx.x;
  const int b = blockIdx.y;
  const int blk0 = blockIdx.x * (TILES * 64);
  const int w = t >> 6;
  const int l = t & 63;
  const int row16 = l & 15;
  const int kg = l >> 4;

  for (int idx = t; idx < 2048; idx += 256) {
    const int c = idx >> 7, chunk = idx & 127;
    xlds4[idx] = *(const int4*)((const char*)(params +
                                              (size_t)(b * 16 + c) * PSTRIDE +
                                              612) +
                                chunk * 16);
  }
  for (int idx = t; idx < 16 * 32; idx += 256) {
    zlds[idx] =
        -params[(size_t)(b * 16 + (idx >> 5)) * PSTRIDE + 576 + (idx & 31)];
  }
  if (t < 16) c0lds[t] = params[(size_t)(b * 16 + t) * PSTRIDE + 608];

  const _Float16* xl = (const _Float16*)xlds4;
  const int cload = t >> 4;
  const int i4 = (t & 15) * 4;

  for (int tile = 0; tile < TILES; ++tile) {
    const int base = blk0 + tile * 64;
    {
      const float4 v0 =
          *(const float4*)(feat + ((size_t)b * CC + cload) * NN + base + i4);
      const float4 v1 = *(const float4*)(feat +
                                         ((size_t)b * CC + cload + 16) * NN +
                                         base + i4);
      fT[(i4 + 0) * 36 + cload] = v0.x;
      fT[(i4 + 1) * 36 + cload] = v0.y;
      fT[(i4 + 2) * 36 + cload] = v0.z;
      fT[(i4 + 3) * 36 + cload] = v0.w;
      fT[(i4 + 0) * 36 + cload + 16] = v1.x;
      fT[(i4 + 1) * 36 + cload + 16] = v1.y;
      fT[(i4 + 2) * 36 + cload + 16] = v1.z;
      fT[(i4 + 3) * 36 + cload + 16] = v1.w;
      if (t < 64) lab_lds[t] = labels[b * NN + base + t];
    }
    __syncthreads();

    const int eoff = (w * 16 + row16) * 36 + kg * 8;
    const float4 fv0 = *(const float4*)&fT[eoff];
    const float4 fv1 = *(const float4*)&fT[eoff + 4];
    half8 bfr;
    bfr[0] = (_Float16)fv0.x;
    bfr[1] = (_Float16)fv0.y;
    bfr[2] = (_Float16)fv0.z;
    bfr[3] = (_Float16)fv0.w;
    bfr[4] = (_Float16)fv1.x;
    bfr[5] = (_Float16)fv1.y;
    bfr[6] = (_Float16)fv1.z;
    bfr[7] = (_Float16)fv1.w;

    const int lab = lab_lds[w * 16 + row16];

    float lp0 = 0.f, lp1 = 0.f, lp2 = 0.f, lp3 = 0.f;
#pragma unroll
    for (int c = 0; c < 16; ++c) {
      const half8 a0 = *(const half8*)&xl[c * 1024 + (0 * 64 + l) * 8];
      const half8 a1 = *(const half8*)&xl[c * 1024 + (1 * 64 + l) * 8];
      const floatx4 cin0 = *(const floatx4*)&zlds[c * 32 + kg * 4];
      const floatx4 cin1 = *(const floatx4*)&zlds[c * 32 + 16 + kg * 4];
      floatx4 y0 =
          __builtin_amdgcn_mfma_f32_16x16x32_f16(a0, bfr, cin0, 0, 0, 0);
      floatx4 y1 =
          __builtin_amdgcn_mfma_f32_16x16x32_f16(a1, bfr, cin1, 0, 0, 0);
      float q = 0.f;
      q = fmaf(y0[0], y0[0], q);
      q = fmaf(y0[1], y0[1], q);
      q = fmaf(y0[2], y0[2], q);
      q = fmaf(y0[3], y0[3], q);
      q = fmaf(y1[0], y1[0], q);
      q = fmaf(y1[1], y1[1], q);
      q = fmaf(y1[2], y1[2], q);
      q = fmaf(y1[3], y1[3], q);
      q += __shfl_xor(q, 16);
      q += __shfl_xor(q, 32);
      const float lp = c0lds[c] - 0.5f * q;
      const bool own = (c >> 2) == lab;
      const int s = c & 3;
      lp0 = (own && s == 0) ? lp : lp0;
      lp1 = (own && s == 1) ? lp : lp1;
      lp2 = (own && s == 2) ? lp : lp2;
      lp3 = (own && s == 3) ? lp : lp3;
    }

    const float m = fmaxf(fmaxf(lp0, lp1), fmaxf(lp2, lp3));
    const float e0 = expf(lp0 - m), e1 = expf(lp1 - m);
    const float e2 = expf(lp2 - m), e3 = expf(lp3 - m);
    const float inv = 1.f / (e0 + e1 + e2 + e3);
    if (l < 16) {
      *(float4*)(resp + ((size_t)b * NN + base + w * 16 + l) * 4) =
          make_float4(e0 * inv, e1 * inv, e2 * inv, e3 * inv);
    }
    __syncthreads();
  }
}

// ---------------------------------------------------------------------------
extern "C" void kernel_launch(void* const* d_in, const int* in_sizes, int n_in,
                              void* d_out, int out_size, void* d_ws,
                              size_t ws_size, hipStream_t stream) {
  const float* feat = (const float*)d_in[0];
  const int* labels = (const int*)d_in[1];
  float* out = (float*)d_out;

  float* stats = (float*)d_ws;
  float* params = stats + (size_t)NCOMP * SSTRIDE;
  float* resp_ws = params + (size_t)NCOMP * PSTRIDE;
  float* partials = resp_ws + (size_t)BB * NN * 4;

  const size_t base_need_f =
      (size_t)NCOMP * SSTRIDE + (size_t)NCOMP * PSTRIDE + (size_t)BB * NN * 4;
  const size_t need128 =
      (base_need_f + (size_t)BB * NB * 16 * SSTRIDE) * sizeof(float);
  const bool have_resp = ws_size >= base_need_f * sizeof(float);
  float* resp = have_resp ? resp_ws : out;

  const int reduce_blocks = (NCOMP * 1057 + 255) / 256;

  if (ws_size >= need128) {
    gmm_accum_mfma<true, 16>
        <<<dim3(NB, BB), 256, 0, stream>>>(feat, labels, out, partials);
    gmm_reduce<<<reduce_blocks, 256, 0, stream>>>(partials, stats, NB);
    gmm_params<<<NCOMP, 64, 0, stream>>>(stats, params);
    for (int it = 1; it < 3; ++it) {
      gmm_fused<8>
          <<<dim3(NB, BB), 256, 0, stream>>>(feat, labels, params, partials);
      gmm_reduce<<<reduce_blocks, 256, 0, stream>>>(partials, stats, NB);
      gmm_params<<<NCOMP, 64, 0, stream>>>(stats, params);
    }
    gmm_estep_final4<8><<<dim3(NN / 512, BB), 256, 0, stream>>>(feat, params,
                                                                out);
  } else {
    for (int it = 0; it < 3; ++it) {
      hipMemsetAsync(stats, 0, (size_t)NCOMP * SSTRIDE * sizeof(float), stream);
      if (it == 0)
        gmm_accum<true, true, 16>
            <<<dim3(64, BB), 256, 0, stream>>>(feat, labels, resp, stats);
      else
        gmm_accum<false, true, 16>
            <<<dim3(64, BB), 256, 0, stream>>>(feat, labels, resp, stats);
      gmm_params<<<NCOMP, 64, 0, stream>>>(stats, params);
      if (it < 2)
        gmm_estep_own4<8><<<dim3(NN / 512, BB), 256, 0, stream>>>(feat, labels,
                                                                  params, resp);
      else
        gmm_estep_final4<8><<<dim3(NN / 512, BB), 256, 0, stream>>>(
            feat, params, out);
    }
  }
}

// Round 26
// 240.580 us; speedup vs baseline: 1.4294x; 1.0477x over previous
//
#include <hip/hip_runtime.h>
#include <hip/hip_fp16.h>
#include <math.h>

#define BB 4
#define CC 32
#define KK 4
#define SS 4
#define NN 65536

constexpr int NCOMP = 64;
constexpr int SSTRIDE = 1088;
constexpr int PSTRIDE = 1128;
constexpr int NB = 128;
constexpr float EPS_ = 1e-6f;
constexpr float COVREG_ = 1e-4f;
constexpr float LOG2PI_C = 1.8378770664093453f;

typedef _Float16 half8 __attribute__((ext_vector_type(8)));
typedef _Float16 half4 __attribute__((ext_vector_type(4)));
typedef float floatx4 __attribute__((ext_vector_type(4)));

// ---------------------------------------------------------------------------
// Kernel 1: iter-0 stats via MFMA (unchanged).
// ---------------------------------------------------------------------------
template <bool ITER0, int CHUNKS>
__global__ __launch_bounds__(256, 2) void gmm_accum_mfma(
    const float* __restrict__ feat, const int* __restrict__ labels,
    const float* __restrict__ resp, float* __restrict__ partials) {
  __shared__ __align__(16) _Float16 fC[32 * 48];
  __shared__ __align__(16) _Float16 respH[4][32];
  __shared__ __align__(16) _Float16 maskH[4][32];

  const int t = threadIdx.x;
  const int b = blockIdx.y;
  const int blk0 = blockIdx.x * (CHUNKS * 32);
  const int k = t >> 6;
  const int l = t & 63;
  const int row16 = l & 15;
  const int kg = l >> 4;

  floatx4 acc[4][7];
#pragma unroll
  for (int s = 0; s < 4; ++s)
#pragma unroll
    for (int j = 0; j < 7; ++j) acc[s][j] = (floatx4){0.f, 0.f, 0.f, 0.f};

  const int cstage = t >> 3;
  const int n4 = (t & 7) * 4;

  float4 pf;
  float4 presp = make_float4(0, 0, 0, 0);
  int plab = 0;
  pf = *(const float4*)(feat + ((size_t)b * CC + cstage) * NN + blk0 + n4);
  if (t < 32) {
    plab = labels[b * NN + blk0 + t];
    if (!ITER0) presp = *(const float4*)(resp + ((size_t)b * NN + blk0 + t) * 4);
  }

  const half8 hz = {0, 0, 0, 0, 0, 0, 0, 0};

  for (int chunk = 0; chunk < CHUNKS; ++chunk) {
    {
      half4 hv;
      hv[0] = (_Float16)pf.x;
      hv[1] = (_Float16)pf.y;
      hv[2] = (_Float16)pf.z;
      hv[3] = (_Float16)pf.w;
      *(half4*)&fC[cstage * 48 + n4] = hv;
    }
    if (t < 32) {
      if (ITER0) {
        const int cmp = (blk0 + chunk * 32 + t) & 3;
        respH[0][t] = (cmp == 0) ? (_Float16)1 : (_Float16)0;
        respH[1][t] = (cmp == 1) ? (_Float16)1 : (_Float16)0;
        respH[2][t] = (cmp == 2) ? (_Float16)1 : (_Float16)0;
        respH[3][t] = (cmp == 3) ? (_Float16)1 : (_Float16)0;
      } else {
        respH[0][t] = (_Float16)presp.x;
        respH[1][t] = (_Float16)presp.y;
        respH[2][t] = (_Float16)presp.z;
        respH[3][t] = (_Float16)presp.w;
      }
      maskH[0][t] = (plab == 0) ? (_Float16)1 : (_Float16)0;
      maskH[1][t] = (plab == 1) ? (_Float16)1 : (_Float16)0;
      maskH[2][t] = (plab == 2) ? (_Float16)1 : (_Float16)0;
      maskH[3][t] = (plab == 3) ? (_Float16)1 : (_Float16)0;
    }
    __syncthreads();

    if (chunk < CHUNKS - 1) {
      const int n0n = blk0 + (chunk + 1) * 32;
      pf = *(const float4*)(feat + ((size_t)b * CC + cstage) * NN + n0n + n4);
      if (t < 32) {
        plab = labels[b * NN + n0n + t];
        if (!ITER0)
          presp = *(const float4*)(resp + ((size_t)b * NN + n0n + t) * 4);
      }
    }

    const half8 ff0 = *(const half8*)&fC[row16 * 48 + kg * 8];
    const half8 ff1 = *(const half8*)&fC[(row16 + 16) * 48 + kg * 8];

    const half8 mh = *(const half8*)&maskH[k][kg * 8];
    const half8 H0 = ff0 * mh;
    const half8 H1 = ff1 * mh;
    const half8 agB = (row16 == 0) ? mh : hz;

#pragma unroll
    for (int s = 0; s < 4; ++s) {
      const half8 rh = *(const half8*)&respH[s][kg * 8];
      const half8 G0 = ff0 * rh;
      const half8 G1 = ff1 * rh;
      const half8 agA = (row16 == 0) ? rh : hz;
      acc[s][0] =
          __builtin_amdgcn_mfma_f32_16x16x32_f16(G0, H0, acc[s][0], 0, 0, 0);
      acc[s][1] =
          __builtin_amdgcn_mfma_f32_16x16x32_f16(G0, H1, acc[s][1], 0, 0, 0);
      acc[s][2] =
          __builtin_amdgcn_mfma_f32_16x16x32_f16(G1, H0, acc[s][2], 0, 0, 0);
      acc[s][3] =
          __builtin_amdgcn_mfma_f32_16x16x32_f16(G1, H1, acc[s][3], 0, 0, 0);
      acc[s][4] =
          __builtin_amdgcn_mfma_f32_16x16x32_f16(G0, agB, acc[s][4], 0, 0, 0);
      acc[s][5] =
          __builtin_amdgcn_mfma_f32_16x16x32_f16(G1, agB, acc[s][5], 0, 0, 0);
      acc[s][6] =
          __builtin_amdgcn_mfma_f32_16x16x32_f16(agA, agB, acc[s][6], 0, 0, 0);
    }
    __syncthreads();
  }

#pragma unroll
  for (int s = 0; s < 4; ++s) {
    float* sg = partials + ((size_t)(b * gridDim.x + blockIdx.x) * 16 +
                            (k * 4 + s)) *
                               SSTRIDE;
    const int dr = kg * 4;
#pragma unroll
    for (int r = 0; r < 4; ++r) {
      sg[(dr + r) * 32 + row16] = acc[s][0][r];
      sg[(dr + r) * 32 + 16 + row16] = acc[s][1][r];
      sg[(16 + dr + r) * 32 + row16] = acc[s][2][r];
      sg[(16 + dr + r) * 32 + 16 + row16] = acc[s][3][r];
    }
    if (row16 == 0) {
#pragma unroll
      for (int r = 0; r < 4; ++r) {
        sg[1024 + dr + r] = acc[s][4][r];
        sg[1024 + 16 + dr + r] = acc[s][5][r];
      }
    }
    if (l == 0) sg[1056] = acc[s][6][0];
  }
}

// ---------------------------------------------------------------------------
// Kernel F: fused E+M (R23/R25 structure) + T5 s_setprio around the MFMA
// clusters (2 independent blocks/CU => phase-diverse waves: setprio regime).
// ---------------------------------------------------------------------------
template <int TILES>
__global__ __launch_bounds__(256, 2) void gmm_fused(
    const float* __restrict__ feat, const int* __restrict__ labels,
    const float* __restrict__ params, float* __restrict__ partials) {
  __shared__ __align__(16) _Float16 fTd[2 * 64 * 56];
  __shared__ __align__(16) _Float16 fCd[2 * 32 * 72];
  __shared__ int4 xlds4[2048];
  __shared__ float zlds[16 * 32];  // -z
  __shared__ float c0lds[16];
  __shared__ int lab_lds[2][64];
  __shared__ __align__(16) _Float16 respHd[2][4][64];
  __shared__ __align__(16) _Float16 maskHd[2][4][64];

  const int t = threadIdx.x;
  const int b = blockIdx.y;
  const int blk0 = blockIdx.x * (TILES * 64);
  const int w = t >> 6;
  const int l = t & 63;
  const int row16 = l & 15;
  const int kg = l >> 4;

  for (int idx = t; idx < 2048; idx += 256) {
    const int c = idx >> 7, chunk = idx & 127;
    xlds4[idx] = *(const int4*)((const char*)(params +
                                              (size_t)(b * 16 + c) * PSTRIDE +
                                              612) +
                                chunk * 16);
  }
  for (int idx = t; idx < 16 * 32; idx += 256) {
    zlds[idx] =
        -params[(size_t)(b * 16 + (idx >> 5)) * PSTRIDE + 576 + (idx & 31)];
  }
  if (t < 16) c0lds[t] = params[(size_t)(b * 16 + t) * PSTRIDE + 608];

  const _Float16* xl = (const _Float16*)xlds4;
  const int cload = t >> 4;
  const int i4 = (t & 15) * 4;
  const half8 hz = {0, 0, 0, 0, 0, 0, 0, 0};

  floatx4 acc[4][7];
#pragma unroll
  for (int s = 0; s < 4; ++s)
#pragma unroll
    for (int j = 0; j < 7; ++j) acc[s][j] = (floatx4){0.f, 0.f, 0.f, 0.f};

  float4 pv0 = *(const float4*)(feat + ((size_t)b * CC + cload) * NN + blk0 + i4);
  float4 pv1 =
      *(const float4*)(feat + ((size_t)b * CC + cload + 16) * NN + blk0 + i4);
  int plab = (t < 64) ? labels[b * NN + blk0 + t] : 0;

  for (int tile = 0; tile < TILES; ++tile) {
    const int base = blk0 + tile * 64;
    const int bs = tile & 1;
    _Float16* fT = &fTd[bs * (64 * 56)];
    _Float16* fC = &fCd[bs * (32 * 72)];

    {
      const _Float16 h0x = (_Float16)pv0.x, h0y = (_Float16)pv0.y;
      const _Float16 h0z = (_Float16)pv0.z, h0w = (_Float16)pv0.w;
      const _Float16 h1x = (_Float16)pv1.x, h1y = (_Float16)pv1.y;
      const _Float16 h1z = (_Float16)pv1.z, h1w = (_Float16)pv1.w;
      fT[(i4 + 0) * 56 + cload] = h0x;
      fT[(i4 + 1) * 56 + cload] = h0y;
      fT[(i4 + 2) * 56 + cload] = h0z;
      fT[(i4 + 3) * 56 + cload] = h0w;
      fT[(i4 + 0) * 56 + cload + 16] = h1x;
      fT[(i4 + 1) * 56 + cload + 16] = h1y;
      fT[(i4 + 2) * 56 + cload + 16] = h1z;
      fT[(i4 + 3) * 56 + cload + 16] = h1w;
      half4 a, c2;
      a[0] = h0x; a[1] = h0y; a[2] = h0z; a[3] = h0w;
      c2[0] = h1x; c2[1] = h1y; c2[2] = h1z; c2[3] = h1w;
      *(half4*)&fC[cload * 72 + i4] = a;
      *(half4*)&fC[(cload + 16) * 72 + i4] = c2;
      if (t < 64) lab_lds[bs][t] = plab;
    }
    __syncthreads();  // sync1

    if (tile < TILES - 1) {
      const int nb2 = base + 64;
      pv0 = *(const float4*)(feat + ((size_t)b * CC + cload) * NN + nb2 + i4);
      pv1 = *(const float4*)(feat + ((size_t)b * CC + cload + 16) * NN + nb2 +
                             i4);
      if (t < 64) plab = labels[b * NN + nb2 + t];
    }

    // ---- E-core ----
    const half8 bfr = *(const half8*)&fT[(w * 16 + row16) * 56 + kg * 8];
    const int lab = lab_lds[bs][w * 16 + row16];

    float lp0 = 0.f, lp1 = 0.f, lp2 = 0.f, lp3 = 0.f;
    __builtin_amdgcn_s_setprio(1);
#pragma unroll
    for (int c = 0; c < 16; ++c) {
      const half8 a0 = *(const half8*)&xl[c * 1024 + (0 * 64 + l) * 8];
      const half8 a1 = *(const half8*)&xl[c * 1024 + (1 * 64 + l) * 8];
      const floatx4 cin0 = *(const floatx4*)&zlds[c * 32 + kg * 4];
      const floatx4 cin1 = *(const floatx4*)&zlds[c * 32 + 16 + kg * 4];
      floatx4 y0 =
          __builtin_amdgcn_mfma_f32_16x16x32_f16(a0, bfr, cin0, 0, 0, 0);
      floatx4 y1 =
          __builtin_amdgcn_mfma_f32_16x16x32_f16(a1, bfr, cin1, 0, 0, 0);
      float q = 0.f;
      q = fmaf(y0[0], y0[0], q);
      q = fmaf(y0[1], y0[1], q);
      q = fmaf(y0[2], y0[2], q);
      q = fmaf(y0[3], y0[3], q);
      q = fmaf(y1[0], y1[0], q);
      q = fmaf(y1[1], y1[1], q);
      q = fmaf(y1[2], y1[2], q);
      q = fmaf(y1[3], y1[3], q);
      q += __shfl_xor(q, 16);
      q += __shfl_xor(q, 32);
      const float lp = c0lds[c] - 0.5f * q;
      const bool own = (c >> 2) == lab;
      const int s = c & 3;
      lp0 = (own && s == 0) ? lp : lp0;
      lp1 = (own && s == 1) ? lp : lp1;
      lp2 = (own && s == 2) ? lp : lp2;
      lp3 = (own && s == 3) ? lp : lp3;
    }
    __builtin_amdgcn_s_setprio(0);

    {
      const float m = fmaxf(fmaxf(lp0, lp1), fmaxf(lp2, lp3));
      const float e0 = expf(lp0 - m), e1 = expf(lp1 - m);
      const float e2 = expf(lp2 - m), e3 = expf(lp3 - m);
      const float inv = 1.f / (e0 + e1 + e2 + e3);
      if (l < 16) {
        const int e = w * 16 + l;
        respHd[bs][0][e] = (_Float16)(e0 * inv);
        respHd[bs][1][e] = (_Float16)(e1 * inv);
        respHd[bs][2][e] = (_Float16)(e2 * inv);
        respHd[bs][3][e] = (_Float16)(e3 * inv);
      }
      if (t < 64) {
        const int lb2 = lab_lds[bs][t];
        maskHd[bs][0][t] = (lb2 == 0) ? (_Float16)1 : (_Float16)0;
        maskHd[bs][1][t] = (lb2 == 1) ? (_Float16)1 : (_Float16)0;
        maskHd[bs][2][t] = (lb2 == 2) ? (_Float16)1 : (_Float16)0;
        maskHd[bs][3][t] = (lb2 == 3) ? (_Float16)1 : (_Float16)0;
      }
    }
    __syncthreads();  // sync2

    // ---- M-core ----
    __builtin_amdgcn_s_setprio(1);
#pragma unroll
    for (int h = 0; h < 2; ++h) {
      const int eb = h * 32;
      const half8 ff0 = *(const half8*)&fC[row16 * 72 + eb + kg * 8];
      const half8 ff1 = *(const half8*)&fC[(row16 + 16) * 72 + eb + kg * 8];

      const half8 mh = *(const half8*)&maskHd[bs][w][eb + kg * 8];
      const half8 H0 = ff0 * mh;
      const half8 H1 = ff1 * mh;
      const half8 agB = (row16 == 0) ? mh : hz;

#pragma unroll
      for (int s = 0; s < 4; ++s) {
        const half8 rh = *(const half8*)&respHd[bs][s][eb + kg * 8];
        const half8 G0 = ff0 * rh;
        const half8 G1 = ff1 * rh;
        const half8 agA = (row16 == 0) ? rh : hz;
        acc[s][0] =
            __builtin_amdgcn_mfma_f32_16x16x32_f16(G0, H0, acc[s][0], 0, 0, 0);
        acc[s][1] =
            __builtin_amdgcn_mfma_f32_16x16x32_f16(G0, H1, acc[s][1], 0, 0, 0);
        acc[s][2] =
            __builtin_amdgcn_mfma_f32_16x16x32_f16(G1, H0, acc[s][2], 0, 0, 0);
        acc[s][3] =
            __builtin_amdgcn_mfma_f32_16x16x32_f16(G1, H1, acc[s][3], 0, 0, 0);
        acc[s][4] =
            __builtin_amdgcn_mfma_f32_16x16x32_f16(G0, agB, acc[s][4], 0, 0, 0);
        acc[s][5] =
            __builtin_amdgcn_mfma_f32_16x16x32_f16(G1, agB, acc[s][5], 0, 0, 0);
        acc[s][6] = __builtin_amdgcn_mfma_f32_16x16x32_f16(agA, agB, acc[s][6],
                                                           0, 0, 0);
      }
    }
    __builtin_amdgcn_s_setprio(0);
  }

#pragma unroll
  for (int s = 0; s < 4; ++s) {
    float* sg = partials + ((size_t)(b * gridDim.x + blockIdx.x) * 16 +
                            (w * 4 + s)) *
                               SSTRIDE;
    const int dr = kg * 4;
#pragma unroll
    for (int r = 0; r < 4; ++r) {
      sg[(dr + r) * 32 + row16] = acc[s][0][r];
      sg[(dr + r) * 32 + 16 + row16] = acc[s][1][r];
      sg[(16 + dr + r) * 32 + row16] = acc[s][2][r];
      sg[(16 + dr + r) * 32 + 16 + row16] = acc[s][3][r];
    }
    if (row16 == 0) {
#pragma unroll
      for (int r = 0; r < 4; ++r) {
        sg[1024 + dr + r] = acc[s][4][r];
        sg[1024 + 16 + dr + r] = acc[s][5][r];
      }
    }
    if (l == 0) sg[1056] = acc[s][6][0];
  }
}

// ---------------------------------------------------------------------------
// Kernel 1b: reduce block-partials -> stats (R23 parallel version).
// ---------------------------------------------------------------------------
__global__ __launch_bounds__(256) void gmm_reduce(const float* __restrict__ part,
                                                  float* __restrict__ stats,
                                                  int nb) {
  const int idx = blockIdx.x * 256 + threadIdx.x;
  if (idx >= NCOMP * 1057) return;
  const int comp = idx / 1057;
  const int cell = idx - comp * 1057;
  const int b = comp >> 4, cl = comp & 15;
  const float* src = part + ((size_t)(b * nb) * 16 + cl) * SSTRIDE + cell;
  const size_t stride = (size_t)16 * SSTRIDE;
  float s0 = 0.f, s1 = 0.f;
#pragma unroll 8
  for (int blk = 0; blk < nb; blk += 2) {
    s0 += src[(size_t)blk * stride];
    s1 += src[(size_t)(blk + 1) * stride];
  }
  stats[(size_t)comp * SSTRIDE + cell] = s0 + s1;
}

// ---------------------------------------------------------------------------
// Kernel 2: params via register/shfl Cholesky.  DEAD-CODE REMOVED: the fp32
// packed-X write (pg[0..575]) — no consumer since R14 (all E/M kernels read
// only fp16 X @612, z @576, c0 @608).  Cuts 576 serial global stores per
// comp in a 1-wave latency-exposed kernel.
// ---------------------------------------------------------------------------
__global__ __launch_bounds__(64) void gmm_params(const float* __restrict__ stats,
                                                 float* __restrict__ params) {
  __shared__ float Xl[32 * 33];
  __shared__ float mul[32];

  const int t = threadIdx.x;
  const int i = t & 31;
  const int comp = blockIdx.x;
  const float* sg = stats + (size_t)comp * SSTRIDE;

  const float w = sg[1056];
  const float invw = 1.f / (w + EPS_);
  const float mu_i = sg[1024 + i] * invw;

  float a[32];
#pragma unroll
  for (int j4 = 0; j4 < 8; ++j4) {
    const float4 v = *(const float4*)(sg + i * 32 + 4 * j4);
    a[4 * j4 + 0] = v.x;
    a[4 * j4 + 1] = v.y;
    a[4 * j4 + 2] = v.z;
    a[4 * j4 + 3] = v.w;
  }
#pragma unroll
  for (int j = 0; j < 32; ++j) {
    const float muj = sg[1024 + j] * invw;
    float v = fmaf(a[j], invw, -mu_i * muj);
    v = (j == i) ? v + COVREG_ : v;
    a[j] = v;
  }

  float ldet = 0.f;
  float rd[32];
#pragma unroll
  for (int j = 0; j < 32; ++j) {
    const float diag = __shfl(a[j], j);
    ldet += logf(diag);
    const float rinv = rsqrtf(diag);
    rd[j] = rinv;
    const float lij = a[j] * rinv;
    a[j] = (i >= j) ? lij : a[j];
#pragma unroll
    for (int m = j + 1; m < 32; ++m) {
      const float Lmj = __shfl(lij, m);
      a[m] = (i >= m) ? fmaf(-lij, Lmj, a[m]) : a[m];
    }
  }

  // inversion with 4-way ILP on the r-chain
  float x[32];
#pragma unroll
  for (int m = 0; m < 32; ++m) {
    float s0 = (m == i) ? 1.f : 0.f, s1 = 0.f, s2 = 0.f, s3 = 0.f;
#pragma unroll
    for (int r = 0; r < m; ++r) {
      const float Lmr = __shfl(a[r], m);
      const float p = -Lmr * x[r];
      if ((r & 3) == 0) s0 += p;
      else if ((r & 3) == 1) s1 += p;
      else if ((r & 3) == 2) s2 += p;
      else s3 += p;
    }
    x[m] = ((s0 + s1) + (s2 + s3)) * rd[m];
  }

  if (t < 32) {
#pragma unroll
    for (int m = 0; m < 32; ++m) Xl[m * 33 + i] = x[m];
    mul[i] = mu_i;
  }
  __syncthreads();

  float* pg = params + (size_t)comp * PSTRIDE;
  // fp16 fragment-major X (the only X consumers read)
  {
    __half* xh = (__half*)(pg + 612);
#pragma unroll
    for (int th = 0; th < 2; ++th) {
      const int row = th * 16 + (t & 15);
      const int k0 = (t >> 4) * 8;
#pragma unroll
      for (int j = 0; j < 8; ++j) {
        const int k = k0 + j;
        const float v = (k <= row) ? Xl[row * 33 + k] : 0.f;
        xh[(th * 64 + t) * 8 + j] = __float2half(v);
      }
    }
  }
  if (t < 32) {
    float z = 0.f;
    for (int j = 0; j <= t; ++j) z += Xl[t * 33 + j] * mul[j];
    pg[576 + t] = z;
  }
  if (t == 0) {
    const int sib = comp & ~3;
    float wsum = 0.f;
    for (int s2 = 0; s2 < 4; ++s2)
      wsum += stats[(size_t)(sib + s2) * SSTRIDE + 1056];
    const float pi = (w + EPS_) / (wsum + SS * EPS_);
    pg[608] = logf(pi) - 0.5f * (CC * LOG2PI_C + ldet);
  }
}

// ---------------------------------------------------------------------------
// Kernel 3b: final E-step (R23 structure) + setprio around the MFMA cluster.
// ---------------------------------------------------------------------------
template <int TILES>
__global__ __launch_bounds__(256, 2) void gmm_estep_final4(
    const float* __restrict__ feat, const float* __restrict__ params,
    float* __restrict__ out) {
  __shared__ __align__(16) _Float16 fTd[2 * 64 * 56];
  __shared__ int4 xlds4[2048];
  __shared__ float zlds[16 * 32];  // -z
  __shared__ float c0lds[16];

  const int t = threadIdx.x;
  const int b = blockIdx.y;
  const int blk0 = blockIdx.x * (TILES * 64);
  const int w = t >> 6;
  const int l = t & 63;
  const int row16 = l & 15;
  const int kg = l >> 4;

  for (int idx = t; idx < 2048; idx += 256) {
    const int c = idx >> 7, chunk = idx & 127;
    xlds4[idx] = *(const int4*)((const char*)(params +
                                              (size_t)(b * 16 + c) * PSTRIDE +
                                              612) +
                                chunk * 16);
  }
  for (int idx = t; idx < 16 * 32; idx += 256) {
    zlds[idx] =
        -params[(size_t)(b * 16 + (idx >> 5)) * PSTRIDE + 576 + (idx & 31)];
  }
  if (t < 16) c0lds[t] = params[(size_t)(b * 16 + t) * PSTRIDE + 608];

  const _Float16* xl = (const _Float16*)xlds4;
  const int cload = t >> 4;
  const int i4 = (t & 15) * 4;

  float4 pv0 = *(const float4*)(feat + ((size_t)b * CC + cload) * NN + blk0 + i4);
  float4 pv1 =
      *(const float4*)(feat + ((size_t)b * CC + cload + 16) * NN + blk0 + i4);

  for (int tile = 0; tile < TILES; ++tile) {
    const int base = blk0 + tile * 64;
    const int bs = tile & 1;
    _Float16* fT = &fTd[bs * (64 * 56)];
    {
      fT[(i4 + 0) * 56 + cload] = (_Float16)pv0.x;
      fT[(i4 + 1) * 56 + cload] = (_Float16)pv0.y;
      fT[(i4 + 2) * 56 + cload] = (_Float16)pv0.z;
      fT[(i4 + 3) * 56 + cload] = (_Float16)pv0.w;
      fT[(i4 + 0) * 56 + cload + 16] = (_Float16)pv1.x;
      fT[(i4 + 1) * 56 + cload + 16] = (_Float16)pv1.y;
      fT[(i4 + 2) * 56 + cload + 16] = (_Float16)pv1.z;
      fT[(i4 + 3) * 56 + cload + 16] = (_Float16)pv1.w;
    }
    __syncthreads();

    if (tile < TILES - 1) {
      const int nb2 = base + 64;
      pv0 = *(const float4*)(feat + ((size_t)b * CC + cload) * NN + nb2 + i4);
      pv1 = *(const float4*)(feat + ((size_t)b * CC + cload + 16) * NN + nb2 +
                             i4);
    }

    const half8 bfr = *(const half8*)&fT[(w * 16 + row16) * 56 + kg * 8];

    float lp[16];
    __builtin_amdgcn_s_setprio(1);
#pragma unroll
    for (int c = 0; c < 16; ++c) {
      const half8 a0 = *(const half8*)&xl[c * 1024 + (0 * 64 + l) * 8];
      const half8 a1 = *(const half8*)&xl[c * 1024 + (1 * 64 + l) * 8];
      const floatx4 cin0 = *(const floatx4*)&zlds[c * 32 + kg * 4];
      const floatx4 cin1 = *(const floatx4*)&zlds[c * 32 + 16 + kg * 4];
      floatx4 y0 =
          __builtin_amdgcn_mfma_f32_16x16x32_f16(a0, bfr, cin0, 0, 0, 0);
      floatx4 y1 =
          __builtin_amdgcn_mfma_f32_16x16x32_f16(a1, bfr, cin1, 0, 0, 0);
      float q = 0.f;
      q = fmaf(y0[0], y0[0], q);
      q = fmaf(y0[1], y0[1], q);
      q = fmaf(y0[2], y0[2], q);
      q = fmaf(y0[3], y0[3], q);
      q = fmaf(y1[0], y1[0], q);
      q = fmaf(y1[1], y1[1], q);
      q = fmaf(y1[2], y1[2], q);
      q = fmaf(y1[3], y1[3], q);
      q += __shfl_xor(q, 16);
      q += __shfl_xor(q, 32);
      lp[c] = c0lds[c] - 0.5f * q;
    }
    __builtin_amdgcn_s_setprio(0);

    float cll[4];
#pragma unroll
    for (int k = 0; k < 4; ++k) {
      const float m = fmaxf(fmaxf(lp[4 * k + 0], lp[4 * k + 1]),
                            fmaxf(lp[4 * k + 2], lp[4 * k + 3]));
      const float s = expf(lp[4 * k + 0] - m) + expf(lp[4 * k + 1] - m) +
                      expf(lp[4 * k + 2] - m) + expf(lp[4 * k + 3] - m);
      cll[k] = m + logf(s);
    }
    const float m = fmaxf(fmaxf(cll[0], cll[1]), fmaxf(cll[2], cll[3]));
    const float e0 = expf(cll[0] - m), e1 = expf(cll[1] - m);
    const float e2 = expf(cll[2] - m), e3 = expf(cll[3] - m);
    const float inv = 1.f / (e0 + e1 + e2 + e3);
    if (l < 16) {
      const int n = base + w * 16 + l;
      out[((size_t)b * KK + 0) * NN + n] = e0 * inv;
      out[((size_t)b * KK + 1) * NN + n] = e1 * inv;
      out[((size_t)b * KK + 2) * NN + n] = e2 * inv;
      out[((size_t)b * KK + 3) * NN + n] = e3 * inv;
    }
  }
}

// ---------------------------------------------------------------------------
// Atomic fallback path (unchanged).
// ---------------------------------------------------------------------------
template <bool ITER0, bool ATOMIC, int TILES>
__global__ __launch_bounds__(256, 1) void gmm_accum(
    const float* __restrict__ feat, const int* __restrict__ labels,
    const float* __restrict__ resp, float* __restrict__ outbuf) {
  __shared__ float fT[64 * 36];
  __shared__ float resp_lds[64 * 4];
  __shared__ int lab_lds[64];

  const int t = threadIdx.x;
  const int b = blockIdx.y;
  const int blk0 = blockIdx.x * (TILES * 64);

  const int wv = t >> 6;
  const int l = t & 63;
  const int sc = (t >> 4) & 3;
  const int p = t & 15;
  const int a0 = (p >> 2) * 8;
  const int b0 = (p & 3) * 8;

  float acc[8][8];
#pragma unroll
  for (int x = 0; x < 8; ++x)
#pragma unroll
    for (int y = 0; y < 8; ++y) acc[x][y] = 0.f;
  float sx[8] = {0, 0, 0, 0, 0, 0, 0, 0};
  float wacc = 0.f;

  const int cload = t >> 4;
  const int i4 = (t & 15) * 4;

  float4 pf0, pf1;
  float4 presp = make_float4(0, 0, 0, 0);
  int plab = 0;
  {
    const int n0 = blk0;
    pf0 = *(const float4*)(feat + ((size_t)b * CC + cload) * NN + n0 + i4);
    pf1 = *(const float4*)(feat + ((size_t)b * CC + cload + 16) * NN + n0 + i4);
    if (t < 64) {
      plab = labels[b * NN + n0 + t];
      if (!ITER0)
        presp = *(const float4*)(resp + ((size_t)b * NN + n0 + t) * 4);
    }
  }

  for (int tile = 0; tile < TILES; ++tile) {
    fT[(i4 + 0) * 36 + cload] = pf0.x;
    fT[(i4 + 1) * 36 + cload] = pf0.y;
    fT[(i4 + 2) * 36 + cload] = pf0.z;
    fT[(i4 + 3) * 36 + cload] = pf0.w;
    fT[(i4 + 0) * 36 + cload + 16] = pf1.x;
    fT[(i4 + 1) * 36 + cload + 16] = pf1.y;
    fT[(i4 + 2) * 36 + cload + 16] = pf1.z;
    fT[(i4 + 3) * 36 + cload + 16] = pf1.w;
    if (t < 64) {
      lab_lds[t] = plab;
      if (ITER0) {
        const int cmp = (blk0 + tile * 64 + t) & 3;
        resp_lds[t * 4 + 0] = (cmp == 0) ? 1.f : 0.f;
        resp_lds[t * 4 + 1] = (cmp == 1) ? 1.f : 0.f;
        resp_lds[t * 4 + 2] = (cmp == 2) ? 1.f : 0.f;
        resp_lds[t * 4 + 3] = (cmp == 3) ? 1.f : 0.f;
      } else {
        resp_lds[t * 4 + 0] = presp.x;
        resp_lds[t * 4 + 1] = presp.y;
        resp_lds[t * 4 + 2] = presp.z;
        resp_lds[t * 4 + 3] = presp.w;
      }
    }
    __syncthreads();
    if (tile < TILES - 1) {
      const int n0 = blk0 + (tile + 1) * 64;
      pf0 = *(const float4*)(feat + ((size_t)b * CC + cload) * NN + n0 + i4);
      pf1 =
          *(const float4*)(feat + ((size_t)b * CC + cload + 16) * NN + n0 + i4);
      if (t < 64) {
        plab = labels[b * NN + n0 + t];
        if (!ITER0)
          presp = *(const float4*)(resp + ((size_t)b * NN + n0 + t) * 4);
      }
    }

    unsigned long long m = __ballot(lab_lds[l] == wv);
    while (m) {
      const int i = __builtin_ctzll(m);
      m &= m - 1;
      const float rs = resp_lds[i * 4 + sc];
      const float4 ra0 = *(const float4*)&fT[i * 36 + a0];
      const float4 ra1 = *(const float4*)&fT[i * 36 + a0 + 4];
      const float4 rb0 = *(const float4*)&fT[i * 36 + b0];
      const float4 rb1 = *(const float4*)&fT[i * 36 + b0 + 4];
      const float ra[8] = {ra0.x, ra0.y, ra0.z, ra0.w,
                           ra1.x, ra1.y, ra1.z, ra1.w};
      const float rb[8] = {rb0.x, rb0.y, rb0.z, rb0.w,
                           rb1.x, rb1.y, rb1.z, rb1.w};
#pragma unroll
      for (int x = 0; x < 8; ++x) {
        const float v = rs * ra[x];
#pragma unroll
        for (int y = 0; y < 8; ++y) acc[x][y] = fmaf(v, rb[y], acc[x][y]);
      }
#pragma unroll
      for (int y = 0; y < 8; ++y) sx[y] = fmaf(rs, rb[y], sx[y]);
      wacc += rs;
    }
    __syncthreads();
  }

  if (ATOMIC) {
    float* sg = outbuf + ((size_t)(b * KK + wv) * SS + sc) * SSTRIDE;
#pragma unroll
    for (int x = 0; x < 8; ++x)
#pragma unroll
      for (int y = 0; y < 8; ++y)
        atomicAdd(sg + (a0 + x) * 32 + b0 + y, acc[x][y]);
    if (p < 4) {
#pragma unroll
      for (int y = 0; y < 8; ++y) atomicAdd(sg + 1024 + b0 + y, sx[y]);
    }
    if (p == 0) atomicAdd(sg + 1056, wacc);
  } else {
    const int nb = NN / (TILES * 64);
    float* sg = outbuf + ((size_t)(b * nb + blockIdx.x) * 16 + (wv * 4 + sc)) *
                             SSTRIDE;
#pragma unroll
    for (int x = 0; x < 8; ++x)
#pragma unroll
      for (int y = 0; y < 8; ++y) sg[(a0 + x) * 32 + b0 + y] = acc[x][y];
    if (p < 4) {
#pragma unroll
      for (int y = 0; y < 8; ++y) sg[1024 + b0 + y] = sx[y];
    }
    if (p == 0) sg[1056] = wacc;
  }
}

template <int TILES>
__global__ __launch_bounds__(256, 2) void gmm_estep_own4(
    const float* __restrict__ feat, const int* __restrict__ labels,
    const float* __restrict__ params, float* __restrict__ resp) {
  __shared__ float fT[64 * 36];
  __shared__ int4 xlds4[2048];
  __shared__ float zlds[16 * 32];
  __shared__ float c0lds[16];
  __shared__ int lab_lds[64];

  const int t = threadIdx.x;
  const int b = blockIdx.y;
  const int blk0 = blockIdx.x * (TILES * 64);
  const int w = t >> 6;
  const int l = t & 63;
  const int row16 = l & 15;
  const int kg = l >> 4;

  for (int idx = t; idx < 2048; idx += 256) {
    const int c = idx >> 7, chunk = idx & 127;
    xlds4[idx] = *(const int4*)((const char*)(params +
                                              (size_t)(b * 16 + c) * PSTRIDE +
                                              612) +
                                chunk * 16);
  }
  for (int idx = t; idx < 16 * 32; idx += 256) {
    zlds[idx] =
        -params[(size_t)(b * 16 + (idx >> 5)) * PSTRIDE + 576 + (idx & 31)];
  }
  if (t < 16) c0lds[t] = params[(size_t)(b * 16 + t) * PSTRIDE + 608];

  const _Float16* xl = (const _Float16*)xlds4;
  const int cload = t >> 4;
  const int i4 = (t & 15) * 4;

  for (int tile = 0; tile < TILES; ++tile) {
    const int base = blk0 + tile * 64;
    {
      const float4 v0 =
          *(const float4*)(feat + ((size_t)b * CC + cload) * NN + base + i4);
      const float4 v1 = *(const float4*)(feat +
                                         ((size_t)b * CC + cload + 16) * NN +
                                         base + i4);
      fT[(i4 + 0) * 36 + cload] = v0.x;
      fT[(i4 + 1) * 36 + cload] = v0.y;
      fT[(i4 + 2) * 36 + cload] = v0.z;
      fT[(i4 + 3) * 36 + cload] = v0.w;
      fT[(i4 + 0) * 36 + cload + 16] = v1.x;
      fT[(i4 + 1) * 36 + cload + 16] = v1.y;
      fT[(i4 + 2) * 36 + cload + 16] = v1.z;
      fT[(i4 + 3) * 36 + cload + 16] = v1.w;
      if (t < 64) lab_lds[t] = labels[b * NN + base + t];
    }
    __syncthreads();

    const int eoff = (w * 16 + row16) * 36 + kg * 8;
    const float4 fv0 = *(const float4*)&fT[eoff];
    const float4 fv1 = *(const float4*)&fT[eoff + 4];
    half8 bfr;
    bfr[0] = (_Float16)fv0.x;
    bfr[1] = (_Float16)fv0.y;
    bfr[2] = (_Float16)fv0.z;
    bfr[3] = (_Float16)fv0.w;
    bfr[4] = (_Float16)fv1.x;
    bfr[5] = (_Float16)fv1.y;
    bfr[6] = (_Float16)fv1.z;
    bfr[7] = (_Float16)fv1.w;

    const int lab = lab_lds[w * 16 + row16];

    float lp0 = 0.f, lp1 = 0.f, lp2 = 0.f, lp3 = 0.f;
#pragma unroll
    for (int c = 0; c < 16; ++c) {
      const half8 a0 = *(const half8*)&xl[c * 1024 + (0 * 64 + l) * 8];
      const half8 a1 = *(const half8*)&xl[c * 1024 + (1 * 64 + l) * 8];
      const floatx4 cin0 = *(const floatx4*)&zlds[c * 32 + kg * 4];
      const floatx4 cin1 = *(const floatx4*)&zlds[c * 32 + 16 + kg * 4];
      floatx4 y0 =
          __builtin_amdgcn_mfma_f32_16x16x32_f16(a0, bfr, cin0, 0, 0, 0);
      floatx4 y1 =
          __builtin_amdgcn_mfma_f32_16x16x32_f16(a1, bfr, cin1, 0, 0, 0);
      float q = 0.f;
      q = fmaf(y0[0], y0[0], q);
      q = fmaf(y0[1], y0[1], q);
      q = fmaf(y0[2], y0[2], q);
      q = fmaf(y0[3], y0[3], q);
      q = fmaf(y1[0], y1[0], q);
      q = fmaf(y1[1], y1[1], q);
      q = fmaf(y1[2], y1[2], q);
      q = fmaf(y1[3], y1[3], q);
      q += __shfl_xor(q, 16);
      q += __shfl_xor(q, 32);
      const float lp = c0lds[c] - 0.5f * q;
      const bool own = (c >> 2) == lab;
      const int s = c & 3;
      lp0 = (own && s == 0) ? lp : lp0;
      lp1 = (own && s == 1) ? lp : lp1;
      lp2 = (own && s == 2) ? lp : lp2;
      lp3 = (own && s == 3) ? lp : lp3;
    }

    const float m = fmaxf(fmaxf(lp0, lp1), fmaxf(lp2, lp3));
    const float e0 = expf(lp0 - m), e1 = expf(lp1 - m);
    const float e2 = expf(lp2 - m), e3 = expf(lp3 - m);
    const float inv = 1.f / (e0 + e1 + e2 + e3);
    if (l < 16) {
      *(float4*)(resp + ((size_t)b * NN + base + w * 16 + l) * 4) =
          make_float4(e0 * inv, e1 * inv, e2 * inv, e3 * inv);
    }
    __syncthreads();
  }
}

// ---------------------------------------------------------------------------
extern "C" void kernel_launch(void* const* d_in, const int* in_sizes, int n_in,
                              void* d_out, int out_size, void* d_ws,
                              size_t ws_size, hipStream_t stream) {
  const float* feat = (const float*)d_in[0];
  const int* labels = (const int*)d_in[1];
  float* out = (float*)d_out;

  float* stats = (float*)d_ws;
  float* params = stats + (size_t)NCOMP * SSTRIDE;
  float* resp_ws = params + (size_t)NCOMP * PSTRIDE;
  float* partials = resp_ws + (size_t)BB * NN * 4;

  const size_t base_need_f =
      (size_t)NCOMP * SSTRIDE + (size_t)NCOMP * PSTRIDE + (size_t)BB * NN * 4;
  const size_t need128 =
      (base_need_f + (size_t)BB * NB * 16 * SSTRIDE) * sizeof(float);
  const bool have_resp = ws_size >= base_need_f * sizeof(float);
  float* resp = have_resp ? resp_ws : out;

  const int reduce_blocks = (NCOMP * 1057 + 255) / 256;

  if (ws_size >= need128) {
    gmm_accum_mfma<true, 16>
        <<<dim3(NB, BB), 256, 0, stream>>>(feat, labels, out, partials);
    gmm_reduce<<<reduce_blocks, 256, 0, stream>>>(partials, stats, NB);
    gmm_params<<<NCOMP, 64, 0, stream>>>(stats, params);
    for (int it = 1; it < 3; ++it) {
      gmm_fused<8>
          <<<dim3(NB, BB), 256, 0, stream>>>(feat, labels, params, partials);
      gmm_reduce<<<reduce_blocks, 256, 0, stream>>>(partials, stats, NB);
      gmm_params<<<NCOMP, 64, 0, stream>>>(stats, params);
    }
    gmm_estep_final4<8><<<dim3(NN / 512, BB), 256, 0, stream>>>(feat, params,
                                                                out);
  } else {
    for (int it = 0; it < 3; ++it) {
      hipMemsetAsync(stats, 0, (size_t)NCOMP * SSTRIDE * sizeof(float), stream);
      if (it == 0)
        gmm_accum<true, true, 16>
            <<<dim3(64, BB), 256, 0, stream>>>(feat, labels, resp, stats);
      else
        gmm_accum<false, true, 16>
            <<<dim3(64, BB), 256, 0, stream>>>(feat, labels, resp, stats);
      gmm_params<<<NCOMP, 64, 0, stream>>>(stats, params);
      if (it < 2)
        gmm_estep_own4<8><<<dim3(NN / 512, BB), 256, 0, stream>>>(feat, labels,
                                                                  params, resp);
      else
        gmm_estep_final4<8><<<dim3(NN / 512, BB), 256, 0, stream>>>(
            feat, params, out);
    }
  }
}